// Round 6
// baseline (12791.987 us; speedup 1.0000x reference)
//
#include <hip/hip_runtime.h>
#include <stdint.h>

#define LOG2E_F 1.4426950408889634f
#define LN2_D   0.6931471805599453
#define SEQLEN 16384
#define NTAGS  1024
#define NSEG   8
#define SEGLEN (SEQLEN / NSEG)   // 2048
#define NREC   (2 * NSEG)        // 16 recurrences (8 fwd + 8 bwd)
#define BPR    16                // blocks per recurrence
#define TPB    512
#define ROWS   64                // rows per block
#define ELDS_BYTES 131072        // 64 rows x 512 u32 (bf16-pair-packed exp(T))
#define GUARD_MAX 500000

// ---- ws layout (bytes) ----
// 0      : wbufs [16][2][1024] u32   (double-buffered packed words: (bf16<<16)|tag)
// 131072 : rm2  [16384] f32
// 196608 : part [16][1024] f32
// 262144 : Ssum [16] double
// 262272 : fs f32 ; 262276 : tsum f32
// 270336 : sbufs [16][2][16] u32     (double-buffered sentinels: tag in low16)

__device__ __forceinline__ uint32_t bf16rne(float x) {
    uint32_t b = __float_as_uint(x);
    b += 0x7FFFu + ((b >> 16) & 1u);
    return b;   // caller takes >>16 (low slot) or &0xFFFF0000 (high slot)
}

__global__ void crf_clear_k(uint32_t* __restrict__ wbufs, uint32_t* __restrict__ sbufs) {
    const int tid = threadIdx.x;
    for (int i = tid; i < NREC * 2 * NTAGS; i += 256)
        __hip_atomic_store(&wbufs[i], 0xFFFFu, __ATOMIC_RELAXED, __HIP_MEMORY_SCOPE_AGENT);
    for (int i = tid; i < NREC * 2 * 16; i += 256)
        __hip_atomic_store(&sbufs[i], 0xFFFFu, __ATOMIC_RELAXED, __HIP_MEMORY_SCOPE_AGENT);
}

__global__ void crf_rowmax_k(const float* __restrict__ feats, float* __restrict__ rm2) {
    const int t = blockIdx.x;
    const int tid = threadIdx.x; // 256
    const float* row = feats + (size_t)t * NTAGS;
    float m = row[tid];
    m = fmaxf(m, row[tid + 256]);
    m = fmaxf(m, row[tid + 512]);
    m = fmaxf(m, row[tid + 768]);
    for (int off = 32; off > 0; off >>= 1) m = fmaxf(m, __shfl_xor(m, off));
    __shared__ float sm[4];
    if ((tid & 63) == 0) sm[tid >> 6] = m;
    __syncthreads();
    if (tid == 0) rm2[t] = fmaxf(fmaxf(sm[0], sm[1]), fmaxf(sm[2], sm[3])) * LOG2E_F;
}

__global__ void crf_emit_k(const float* __restrict__ feats, const int* __restrict__ tags,
                           float* __restrict__ part) {
    __shared__ int tg[1024];
    const int tid = threadIdx.x;          // 256
    const int b = blockIdx.x;             // 64 blocks: 16 t-chunks x 4 col-chunks
    const int cch = b >> 2;
    const int jb = b & 3;
    for (int q = tid; q < 1024; q += 256) tg[q] = tags[cch * 1024 + q];
    __syncthreads();
    const int j = jb * 256 + tid;
    float acc = 0.f;
#pragma unroll 8
    for (int k = 0; k < 1024; ++k) acc += feats[(size_t)tg[k] * NTAGS + j];
    part[cch * NTAGS + j] = acc;          // deterministic fixed-order partials
}

__global__ void crf_trans_k(const float* __restrict__ trans, const int* __restrict__ tags,
                            const int* __restrict__ start_p, float* __restrict__ tsum) {
    __shared__ float red[256];
    const int tid = threadIdx.x;
    const int start = *start_p;
    float acc = 0.f;
    for (int k = 0; k < 64; ++k) {
        const int t = tid * 64 + k;
        const int prev = (t == 0) ? start : tags[t - 1];
        acc += trans[(size_t)tags[t] * NTAGS + prev];
    }
    red[tid] = acc;
    __syncthreads();
    for (int s = 128; s > 0; s >>= 1) { if (tid < s) red[tid] += red[tid + s]; __syncthreads(); }
    if (tid == 0) *tsum = red[0];
}

__global__ __launch_bounds__(TPB, 1) void crf_scan_k(
    const float* __restrict__ feats, const float* __restrict__ trans,
    uint32_t* __restrict__ wbufs, uint32_t* __restrict__ sbufs,
    const float* __restrict__ rm2, double* __restrict__ Ssum)
{
    extern __shared__ uint32_t elds[];      // [64][512] u32: swizzled bf16-pair exp(T)
    __shared__ float w_lds[2][8 * 132];     // double-buffered; stride 132 conflict-free
    __shared__ float wmax_lds[2][8];
    __shared__ int deadf;

    const int tid = threadIdx.x;
    const int wave = tid >> 6;
    const int lane = tid & 63;
    const int rec = blockIdx.x & (NREC - 1);
    const int rank = blockIdx.x >> 4;       // 0..15
    const int seg = rec & (NSEG - 1);
    const int bwd = rec >> 3;               // 0 = forward, 1 = backward (transpose)
    const int a = seg * SEGLEN;
    const int r = tid >> 3;                 // row-in-block 0..63
    const int c = tid & 7;                  // 128-col chunk 0..7
    const int row = rank * ROWS + r;        // global state index
    const bool c0 = (c == 0);
    uint32_t* wbuf = wbufs + rec * (2 * NTAGS);
    uint32_t* sbuf = sbufs + rec * 32;      // [2][16]

    // ---- stage E chunk into LDS as bf16 pairs, +4c u32-swizzle per c-chunk ----
    // fwd: E[row, c*128+k] = exp(T[row, c*128+k]); bwd: exp(T[c*128+k, row]).
    {
        const size_t estride = bwd ? (size_t)NTAGS : 1;
        const float* tp = bwd ? (trans + (size_t)(c * 128) * NTAGS + row)
                              : (trans + (size_t)row * NTAGS + c * 128);
        uint32_t* erow = elds + r * 512 + c * 64;
#pragma unroll 8
        for (int m = 0; m < 64; ++m) {      // pair m = cols {2m, 2m+1} of this chunk
            const float a0 = exp2f(tp[(size_t)(2 * m) * estride] * LOG2E_F);
            const float a1 = exp2f(tp[(size_t)(2 * m + 1) * estride] * LOG2E_F);
            erow[(m + 4 * c) & 63] = (bf16rne(a0) >> 16) | (bf16rne(a1) & 0xFFFF0000u);
        }
    }
    if (tid == 0) deadf = 0;

    // ---- initial publish (tag 0): data words, drain, barrier, sentinel ----
    double S = 0.0;
    if (!bwd) {
        if (c0)
            __hip_atomic_store(&wbuf[row], __float_as_uint(1.0f) & 0xFFFF0000u,
                               __ATOMIC_RELAXED, __HIP_MEMORY_SCOPE_AGENT);
    } else {
        const float C0 = rm2[a + SEGLEN - 1] + 10.0f;
        S = (double)C0;
        if (c0) {
            const float fL = feats[(size_t)(a + SEGLEN - 1) * NTAGS + row] * LOG2E_F;
            __hip_atomic_store(&wbuf[row], bf16rne(exp2f(fL - C0)) & 0xFFFF0000u,
                               __ATOMIC_RELAXED, __HIP_MEMORY_SCOPE_AGENT);
        }
    }
    asm volatile("s_waitcnt vmcnt(0)" ::: "memory");   // all lanes' stores drained
    __syncthreads();
    if (tid == 0)
        __hip_atomic_store(&sbuf[rank], 0u, __ATOMIC_RELAXED, __HIP_MEMORY_SCOPE_AGENT);

    // feat index applied at publish of tag k+1:
    //   fwd: a+k ; bwd: (a+SEGLEN-2)-k while k <= SEGLEN-2 (final publish has no D)
    float featL_cur = 0.f, rm2_cur = 0.f;
    {
        const int f0 = bwd ? (a + SEGLEN - 2) : a;
        rm2_cur = rm2[f0];
        if (c0) featL_cur = feats[(size_t)f0 * NTAGS + row] * LOG2E_F;
    }

    const int i0 = tid * 2;
    const int sidx = (i0 >> 7) * 132 + (i0 & 127);
    const uint32_t* ew = elds + r * 512 + c * 64;

    for (int k = 0; k < SEGLEN; ++k) {
        const uint32_t tag = (uint32_t)k;
        const uint64_t tag2 = (uint64_t)tag | ((uint64_t)tag << 32);
        uint32_t* wb = wbuf + (k & 1) * NTAGS;
        const int kb = k & 1;

        // ---- 1. sentinel spin: wave 0 only (16 lanes x 256 blocks chip-wide) ----
        if (wave == 0) {
            int guard = 0;
            for (;;) {
                uint32_t sv = tag;
                if (lane < BPR)
                    sv = __hip_atomic_load(&sbuf[kb * 16 + lane],
                                           __ATOMIC_RELAXED, __HIP_MEMORY_SCOPE_AGENT);
                if (__all(((sv ^ tag) & 0xFFFFu) == 0u)) break;
                if (++guard > GUARD_MAX) { deadf = 1; break; }
            }
        }
        // prefetch next step's feat/rm2 (off critical path; waits at use)
        float featL_nxt = 0.f, rm2_nxt = 0.f;
        {
            const int kn = k + 1;
            int fn = -1;
            if (kn < SEGLEN) fn = bwd ? ((kn <= SEGLEN - 2) ? (a + SEGLEN - 2 - kn) : -1)
                                      : (a + kn);
            if (fn >= 0) {
                rm2_nxt = rm2[fn];
                if (c0) featL_nxt = feats[(size_t)fn * NTAGS + row] * LOG2E_F;
            }
        }
        __syncthreads();               // A: sentinels seen; deadf visible
        if (deadf) break;              // uniform abort (no hang)

        // ---- 2. bulk load + tag verify (correct regardless of store ordering) ----
        uint32_t wa, wv;
        {
            int guard = 0;
            for (;;) {
                const uint64_t v = __hip_atomic_load((const uint64_t*)&wb[i0],
                                                     __ATOMIC_RELAXED,
                                                     __HIP_MEMORY_SCOPE_AGENT);
                if (((v ^ tag2) & 0x0000FFFF0000FFFFull) == 0ull) {
                    wa = (uint32_t)v; wv = (uint32_t)(v >> 32); break;
                }
                if (++guard > GUARD_MAX) { deadf = 1; wa = wv = 0; break; }
            }
        }
        const float w0f = __uint_as_float(wa & 0xFFFF0000u);
        const float w1f = __uint_as_float(wv & 0xFFFF0000u);
        w_lds[kb][sidx] = w0f; w_lds[kb][sidx + 1] = w1f;
        float m2 = fmaxf(w0f, w1f);
#pragma unroll
        for (int o = 32; o > 0; o >>= 1) m2 = fmaxf(m2, __shfl_xor(m2, o));
        if (lane == 0) wmax_lds[kb][wave] = m2;
        __syncthreads();               // B: w_lds + wmax ready

        float mw = wmax_lds[kb][0];
#pragma unroll
        for (int q = 1; q < 8; ++q) mw = fmaxf(mw, wmax_lds[kb][q]);
        const float C = rm2_cur + __log2f(mw) + 10.0f;  // identical in every block
        S += (double)C;

        // ---- 3. d_row partial: LDS bf16-pair E x LDS f32 w ----
        float acc = 0.f;
        const float* wl = &w_lds[kb][c * 132];
#pragma unroll
        for (int q = 0; q < 16; ++q) {
            const uint4 e4 = *(const uint4*)&ew[(4 * q + 4 * c) & 63];
            const float4 wA = *(const float4*)&wl[8 * q];
            const float4 wB = *(const float4*)&wl[8 * q + 4];
            acc = fmaf(__uint_as_float(e4.x << 16),          wA.x, acc);
            acc = fmaf(__uint_as_float(e4.x & 0xFFFF0000u),  wA.y, acc);
            acc = fmaf(__uint_as_float(e4.y << 16),          wA.z, acc);
            acc = fmaf(__uint_as_float(e4.y & 0xFFFF0000u),  wA.w, acc);
            acc = fmaf(__uint_as_float(e4.z << 16),          wB.x, acc);
            acc = fmaf(__uint_as_float(e4.z & 0xFFFF0000u),  wB.y, acc);
            acc = fmaf(__uint_as_float(e4.w << 16),          wB.z, acc);
            acc = fmaf(__uint_as_float(e4.w & 0xFFFF0000u),  wB.w, acc);
        }
        acc += __shfl_xor(acc, 4);
        acc += __shfl_xor(acc, 2);
        acc += __shfl_xor(acc, 1);     // 8 lanes of a row -> full dot product

        // ---- 4. publish data, drain, barrier, sentinel ----
        if (c0) {
            const float wn = acc * exp2f(featL_cur - C);
            __hip_atomic_store(&wbuf[((k + 1) & 1) * NTAGS + row],
                               (bf16rne(wn) & 0xFFFF0000u) | ((tag + 1u) & 0xFFFFu),
                               __ATOMIC_RELAXED, __HIP_MEMORY_SCOPE_AGENT);
        }
        asm volatile("s_waitcnt vmcnt(0)" ::: "memory");  // wave counter: stores drained
        __syncthreads();               // C: all 64 data words of this block drained
        if (tid == 0)
            __hip_atomic_store(&sbuf[((k + 1) & 1) * 16 + rank], (tag + 1u) & 0xFFFFu,
                               __ATOMIC_RELAXED, __HIP_MEMORY_SCOPE_AGENT);
        featL_cur = featL_nxt; rm2_cur = rm2_nxt;
    }

    if (rank == 0 && tid == 0) Ssum[rec] = S;
}

// Serial stitch: v0 = init; for s: c = LSE(z_s+v)-LSE(z_s); v = y_s + c.
__global__ void crf_stitch_k(const uint32_t* __restrict__ wbufs,
                             const double* __restrict__ Ssum,
                             const float* __restrict__ trans,
                             const int* __restrict__ start_p, const int* __restrict__ stop_p,
                             float* __restrict__ fs_out)
{
    const int j = threadIdx.x;   // 1024
    __shared__ float sred[16];

    auto bmax = [&](float x) -> float {
#pragma unroll
        for (int o = 32; o > 0; o >>= 1) x = fmaxf(x, __shfl_xor(x, o));
        if ((j & 63) == 0) sred[j >> 6] = x;
        __syncthreads();
        float m = sred[0];
#pragma unroll
        for (int q = 1; q < 16; ++q) m = fmaxf(m, sred[q]);
        __syncthreads();
        return m;
    };
    auto bsum = [&](float x) -> float {
#pragma unroll
        for (int o = 32; o > 0; o >>= 1) x += __shfl_xor(x, o);
        if ((j & 63) == 0) sred[j >> 6] = x;
        __syncthreads();
        float s = 0.f;
#pragma unroll
        for (int q = 0; q < 16; ++q) s += sred[q];
        __syncthreads();
        return s;
    };

    float v = (j == *start_p) ? 0.0f : -10000.0f;
    for (int s = 0; s < NSEG; ++s) {
        const float yp = __uint_as_float(wbufs[s * 2048 + j] & 0xFFFF0000u);
        const float zp = __uint_as_float(wbufs[(NSEG + s) * 2048 + j] & 0xFFFF0000u);
        const float y = (float)(LN2_D * ((double)__log2f(yp) + Ssum[s]));
        const float z = (float)(LN2_D * ((double)__log2f(zp) + Ssum[NSEG + s]));
        const float m1 = bmax(z + v);
        const float s1 = bsum(__expf(z + v - m1));
        const float m2 = bmax(z);
        const float s2 = bsum(__expf(z - m2));
        v = y + ((m1 + __logf(s1)) - (m2 + __logf(s2)));
    }
    const float tr = trans[(size_t)(*stop_p) * NTAGS + j];
    const float m = bmax(v + tr);
    const float ss = bsum(__expf(v + tr - m));
    if (j == 0) fs_out[0] = m + __logf(ss);
}

__global__ void crf_out_k(const float* __restrict__ fsp, const float* __restrict__ tsum,
                          const float* __restrict__ part, const float* __restrict__ trans,
                          const int* __restrict__ tags, const int* __restrict__ stop_p,
                          float* __restrict__ out) {
    const int j = threadIdx.x; // 1024
    float e = 0.f;
    for (int cc = 0; cc < 16; ++cc) e += part[cc * NTAGS + j];
    const int stop = *stop_p;
    const int last = tags[SEQLEN - 1];
    out[j] = fsp[0] - (tsum[0] + e + trans[(size_t)stop * NTAGS + last]);
}

extern "C" void kernel_launch(void* const* d_in, const int* in_sizes, int n_in,
                              void* d_out, int out_size, void* d_ws, size_t ws_size,
                              hipStream_t stream) {
    const float* feats = (const float*)d_in[0];
    const float* trans = (const float*)d_in[1];
    const int* tags    = (const int*)d_in[2];
    const int* start_p = (const int*)d_in[3];
    const int* stop_p  = (const int*)d_in[4];
    float* out = (float*)d_out;

    char* ws = (char*)d_ws;
    uint32_t* wbufs = (uint32_t*)(ws + 0);
    float* rm2      = (float*)(ws + 131072);
    float* part     = (float*)(ws + 196608);
    double* Ssum    = (double*)(ws + 262144);
    float* fs       = (float*)(ws + 262272);
    float* tsum     = (float*)(ws + 262276);
    uint32_t* sbufs = (uint32_t*)(ws + 270336);

    (void)hipFuncSetAttribute((const void*)crf_scan_k,
                              hipFuncAttributeMaxDynamicSharedMemorySize, ELDS_BYTES);

    crf_clear_k<<<1, 256, 0, stream>>>(wbufs, sbufs);
    crf_rowmax_k<<<SEQLEN, 256, 0, stream>>>(feats, rm2);
    crf_emit_k<<<64, 256, 0, stream>>>(feats, tags, part);
    crf_trans_k<<<1, 256, 0, stream>>>(trans, tags, start_p, tsum);
    crf_scan_k<<<NREC * BPR, TPB, ELDS_BYTES, stream>>>(feats, trans, wbufs, sbufs, rm2, Ssum);
    crf_stitch_k<<<1, 1024, 0, stream>>>(wbufs, Ssum, trans, start_p, stop_p, fs);
    crf_out_k<<<1, 1024, 0, stream>>>(fs, tsum, part, trans, tags, stop_p, out);
}

// Round 7
// 8515.855 us; speedup vs baseline: 1.5021x; 1.5021x over previous
//
#include <hip/hip_runtime.h>
#include <stdint.h>

#define LOG2E_F 1.4426950408889634f
#define LN2_D   0.6931471805599453
#define SEQLEN 16384
#define NTAGS  1024
#define NSEG   16
#define SEGLEN (SEQLEN / NSEG)   // 1024
#define NREC   (2 * NSEG)        // 32 recurrences (16 fwd + 16 bwd)
#define BPR    8                 // blocks per recurrence (one XCD hosts 4 recs x 8 blocks)
#define TPB    512
#define ROWS   128               // rows per block
#define ELDS_BYTES 131072        // 128 rows x 256 u32 (fp8x4-packed exp(T))
#define FAST_TRIES 1500
#define GUARD_MAX 300000

// ---- ws layout (bytes), total 327976 (< proven 344064) ----
// 0      : wbufs [32][2][1024] u32   (double-buffered packed words: (bf16<<16)|tag)
// 262144 : part [16][1024] f32       (emit partials)
// 327680 : Ssum [32] double
// 327936 : fs f32 ; 327940 : tsum f32 ; 327944 : cnt[8] int (XCD arrival counters)

typedef float f32x2 __attribute__((ext_vector_type(2)));

__device__ __forceinline__ uint32_t bf16rne(float x) {
    uint32_t b = __float_as_uint(x);
    b += 0x7FFFu + ((b >> 16) & 1u);
    return b;
}

#if __has_builtin(__builtin_amdgcn_cvt_pk_fp8_f32) && __has_builtin(__builtin_amdgcn_cvt_pk_f32_fp8)
__device__ __forceinline__ uint32_t pack4_fp8(float x0, float x1, float x2, float x3) {
    int v = __builtin_amdgcn_cvt_pk_fp8_f32(x0, x1, 0, false);
    v = __builtin_amdgcn_cvt_pk_fp8_f32(x2, x3, v, true);
    return (uint32_t)v;
}
#define DEC2LO(u) ((f32x2)__builtin_amdgcn_cvt_pk_f32_fp8((int)(u), false))
#define DEC2HI(u) ((f32x2)__builtin_amdgcn_cvt_pk_f32_fp8((int)(u), true))
#else
__device__ __forceinline__ uint32_t enc1_fp8(float x) {   // x>0, e4m3fn, RNE-ish
    if (x >= 448.f) return 0x7Eu;
    if (x < 0.015625f) { int m = (int)(x * 512.f + 0.5f); return (uint32_t)m; }
    uint32_t u = __float_as_uint(x);
    u += 0x7FFFFu + ((u >> 20) & 1u);
    int e32 = (int)(u >> 23) - 127;
    if (e32 > 8) return 0x7Eu;
    return (uint32_t)(((e32 + 7) << 3) | ((u >> 20) & 7u));
}
__device__ __forceinline__ uint32_t pack4_fp8(float x0, float x1, float x2, float x3) {
    return enc1_fp8(x0) | (enc1_fp8(x1) << 8) | (enc1_fp8(x2) << 16) | (enc1_fp8(x3) << 24);
}
__device__ __forceinline__ float dec1_fp8(uint32_t b) {
    b &= 0xFFu;
    uint32_t e = (b >> 3) & 0xFu, m = b & 7u;
    if (e == 0) return (float)m * 0.001953125f;
    return __uint_as_float(((e + 120u) << 23) | (m << 20));
}
__device__ __forceinline__ f32x2 dec2lo_(uint32_t u) { f32x2 r; r.x = dec1_fp8(u); r.y = dec1_fp8(u >> 8); return r; }
__device__ __forceinline__ f32x2 dec2hi_(uint32_t u) { f32x2 r; r.x = dec1_fp8(u >> 16); r.y = dec1_fp8(u >> 24); return r; }
#define DEC2LO(u) dec2lo_(u)
#define DEC2HI(u) dec2hi_(u)
#endif

__device__ __forceinline__ uint64_t poll2_sc0(const uint32_t* p) {
    uint64_t v;
    asm volatile("global_load_dwordx2 %0, %1, off sc0\n\ts_waitcnt vmcnt(0)"
                 : "=v"(v) : "v"(p) : "memory");
    return v;
}
// dual publish: sc0 (same-XCD L2 fast path) + agent atomic (authoritative, proven).
// Identical bytes -> any coherence interleaving is harmless.
__device__ __forceinline__ void pub(uint32_t* p, uint32_t v) {
    asm volatile("global_store_dword %0, %1, off sc0" :: "v"(p), "v"(v) : "memory");
    __hip_atomic_store(p, v, __ATOMIC_RELAXED, __HIP_MEMORY_SCOPE_AGENT);
}

__global__ void crf_clear_k(uint32_t* __restrict__ wbufs, int* __restrict__ cnt) {
    const int tid = threadIdx.x;
    for (int i = tid; i < NREC * 2 * NTAGS; i += 256)
        __hip_atomic_store(&wbufs[i], 0xFFFFu, __ATOMIC_RELAXED, __HIP_MEMORY_SCOPE_AGENT);
    if (tid < 8) cnt[tid] = 0;
}

__global__ void crf_emit_k(const float* __restrict__ feats, const int* __restrict__ tags,
                           float* __restrict__ part) {
    __shared__ int tg[1024];
    const int tid = threadIdx.x;          // 256
    const int b = blockIdx.x;             // 64 blocks: 16 t-chunks x 4 col-chunks
    const int cch = b >> 2;
    const int jb = b & 3;
    for (int q = tid; q < 1024; q += 256) tg[q] = tags[cch * 1024 + q];
    __syncthreads();
    const int j = jb * 256 + tid;
    float acc = 0.f;
#pragma unroll 8
    for (int k = 0; k < 1024; ++k) acc += feats[(size_t)tg[k] * NTAGS + j];
    part[cch * NTAGS + j] = acc;
}

__global__ void crf_trans_k(const float* __restrict__ trans, const int* __restrict__ tags,
                            const int* __restrict__ start_p, float* __restrict__ tsum) {
    __shared__ float red[256];
    const int tid = threadIdx.x;
    const int start = *start_p;
    float acc = 0.f;
    for (int k = 0; k < 64; ++k) {
        const int t = tid * 64 + k;
        const int prev = (t == 0) ? start : tags[t - 1];
        acc += trans[(size_t)tags[t] * NTAGS + prev];
    }
    red[tid] = acc;
    __syncthreads();
    for (int s = 128; s > 0; s >>= 1) { if (tid < s) red[tid] += red[tid + s]; __syncthreads(); }
    if (tid == 0) *tsum = red[0];
}

__global__ __launch_bounds__(TPB, 1) void crf_scan_k(
    const float* __restrict__ feats, const float* __restrict__ trans,
    uint32_t* __restrict__ wbufs, int* __restrict__ cnt, double* __restrict__ Ssum)
{
    extern __shared__ uint32_t elds[];       // [128][256] u32: rotated fp8x4 exp(T)
    __shared__ float w_lds[2][4 * 260];      // double-buffered; 260-stride per chunk
    __shared__ float wmax_lds[2][8];
    __shared__ int s_aid, deadf;

    const int tid = threadIdx.x;
    const int wave = tid >> 6;

    // ---- XCD-local pooling: rec group lives on ONE XCD (arrival-order, no election)
    if (tid == 0) {
        int xcd = 0;
        asm volatile("s_getreg_b32 %0, hwreg(HW_REG_XCC_ID)" : "=s"(xcd));
        xcd &= 7;
        s_aid = (xcd << 5) + (atomicAdd(&cnt[xcd], 1) & 31);
        deadf = 0;
    }
    __syncthreads();
    const int aid = s_aid;
    const int rec = ((aid >> 5) << 2) + ((aid & 31) >> 3);  // xcd*4 + arrival/8
    const int rank = aid & 7;                               // 0..7 within rec
    const int seg = rec & (NSEG - 1);
    const int bwd = rec >> 4;
    const int a = seg * SEGLEN;
    const int r = tid >> 2;                  // row-in-block 0..127
    const int c = tid & 3;                   // 256-col chunk 0..3
    const int row = rank * ROWS + r;         // global state index
    const bool c0 = (c == 0);
    uint32_t* wbuf = wbufs + rec * (2 * NTAGS);
    const int ROTU = (4 * r + 16 * c) & 63;  // u32-rotation: 4-way (=floor) b128 reads

    // ---- stage E chunk into LDS as fp8x4, rotated ----
    // fwd: E[row, c*256+m] = exp(T[row, m']); bwd: (E^T)[row, m'] = exp(T[m', row]).
    {
        const size_t estride = bwd ? (size_t)NTAGS : 1;
        const float* tp = bwd ? (trans + (size_t)(c * 256) * NTAGS + row)
                              : (trans + (size_t)row * NTAGS + c * 256);
        uint32_t* erow = elds + r * 256 + c * 64;
        for (int q = 0; q < 64; ++q) {
            const float x0 = exp2f(tp[(size_t)(4 * q + 0) * estride] * LOG2E_F);
            const float x1 = exp2f(tp[(size_t)(4 * q + 1) * estride] * LOG2E_F);
            const float x2 = exp2f(tp[(size_t)(4 * q + 2) * estride] * LOG2E_F);
            const float x3 = exp2f(tp[(size_t)(4 * q + 3) * estride] * LOG2E_F);
            erow[(q + ROTU) & 63] = pack4_fp8(x0, x1, x2, x3);
        }
    }

    // ---- initial publish (tag 0) ----
    double S = 0.0;
    if (!bwd) {
        if (c0) pub(&wbuf[row], __float_as_uint(1.0f) & 0xFFFF0000u);
    } else {
        S = 10.0;   // C0
        if (c0) {
            const float fL = feats[(size_t)(a + SEGLEN - 1) * NTAGS + row] * LOG2E_F;
            pub(&wbuf[row], bf16rne(exp2f(fL - 10.0f)) & 0xFFFF0000u);
        }
    }
    __syncthreads();

    // feat index applied at publish of tag k+1:
    //   fwd: a+k ; bwd: (a+SEGLEN-2)-k while k <= SEGLEN-2 (final publish has no D)
    float featL_cur = 0.f;
    if (c0) {
        const int f0 = bwd ? (a + SEGLEN - 2) : a;
        featL_cur = feats[(size_t)f0 * NTAGS + row] * LOG2E_F;
    }

    const int i0 = tid * 2;
    const int cg = i0 >> 8, off = i0 & 255;
    const uint32_t* ew = elds + r * 256 + c * 64;
    int fastok = 1;

    for (int k = 0; k < SEGLEN; ++k) {
        const uint32_t tag = (uint32_t)k;
        const uint64_t tag2 = (uint64_t)tag | ((uint64_t)tag << 32);
        uint32_t* wb = wbuf + (k & 1) * NTAGS;
        const int kb = k & 1;

        // prefetch next step's feat (issues before the poll; waits at use)
        float featL_nxt = 0.f;
        if (c0) {
            const int kn = k + 1;
            int fn = -1;
            if (kn < SEGLEN) fn = bwd ? ((kn <= SEGLEN - 2) ? (a + SEGLEN - 2 - kn) : -1)
                                      : (a + kn);
            if (fn >= 0) featL_nxt = feats[(size_t)fn * NTAGS + row] * LOG2E_F;
        }

        // ---- poll my two packed words: sticky sc0 fast path, agent fallback ----
        uint32_t wa, wv;
        int got = 0;
        if (fastok && k >= 2) {
            for (int it = 0; it < FAST_TRIES; ++it) {
                const uint64_t v = poll2_sc0(&wb[i0]);
                if (((v ^ tag2) & 0x0000FFFF0000FFFFull) == 0ull) {
                    wa = (uint32_t)v; wv = (uint32_t)(v >> 32); got = 1; break;
                }
            }
            if (!got) fastok = 0;   // sticky: never retry the fast path
        }
        if (!got) {
            int guard = 0;
            for (;;) {
                const uint64_t v = __hip_atomic_load((const uint64_t*)&wb[i0],
                                                     __ATOMIC_RELAXED,
                                                     __HIP_MEMORY_SCOPE_AGENT);
                if (((v ^ tag2) & 0x0000FFFF0000FFFFull) == 0ull) {
                    wa = (uint32_t)v; wv = (uint32_t)(v >> 32); break;
                }
                if (++guard > GUARD_MAX) { deadf = 1; wa = wv = 0; break; }
            }
        }

        const float w0f = __uint_as_float(wa & 0xFFFF0000u);
        const float w1f = __uint_as_float(wv & 0xFFFF0000u);
        {
            float* wd = &w_lds[kb][cg * 260 + off];
            wd[0] = w0f; wd[1] = w1f;
        }
        float m2 = fmaxf(w0f, w1f);
#pragma unroll
        for (int o = 32; o > 0; o >>= 1) m2 = fmaxf(m2, __shfl_xor(m2, o));
        if ((tid & 63) == 0) wmax_lds[kb][wave] = m2;
        __syncthreads();               // single barrier per step (dbuf w_lds)
        if (deadf) break;              // uniform abort (no hang)

        float mw = wmax_lds[kb][0];
#pragma unroll
        for (int q = 1; q < 8; ++q) mw = fmaxf(mw, wmax_lds[kb][q]);
        const float C = __log2f(mw) + 10.0f;   // identical in every block of rec
        S += (double)C;

        // ---- d_row partial: LDS fp8 E x LDS f32 w ----
        float acc = 0.f;
        const float* wl = &w_lds[kb][c * 260];
#pragma unroll
        for (int i = 0; i < 16; ++i) {
            const uint4 e4 = *(const uint4*)&ew[(4 * i + ROTU) & 63];
            const float4 wA = *(const float4*)&wl[16 * i];
            const float4 wB = *(const float4*)&wl[16 * i + 4];
            const float4 wC = *(const float4*)&wl[16 * i + 8];
            const float4 wD = *(const float4*)&wl[16 * i + 12];
            f32x2 p;
            p = DEC2LO(e4.x); acc = fmaf(p.x, wA.x, acc); acc = fmaf(p.y, wA.y, acc);
            p = DEC2HI(e4.x); acc = fmaf(p.x, wA.z, acc); acc = fmaf(p.y, wA.w, acc);
            p = DEC2LO(e4.y); acc = fmaf(p.x, wB.x, acc); acc = fmaf(p.y, wB.y, acc);
            p = DEC2HI(e4.y); acc = fmaf(p.x, wB.z, acc); acc = fmaf(p.y, wB.w, acc);
            p = DEC2LO(e4.z); acc = fmaf(p.x, wC.x, acc); acc = fmaf(p.y, wC.y, acc);
            p = DEC2HI(e4.z); acc = fmaf(p.x, wC.z, acc); acc = fmaf(p.y, wC.w, acc);
            p = DEC2LO(e4.w); acc = fmaf(p.x, wD.x, acc); acc = fmaf(p.y, wD.y, acc);
            p = DEC2HI(e4.w); acc = fmaf(p.x, wD.z, acc); acc = fmaf(p.y, wD.w, acc);
        }
        acc += __shfl_xor(acc, 1);
        acc += __shfl_xor(acc, 2);     // 4 c-lanes of a row -> full dot product

        if (c0) {
            const float wn = acc * exp2f(featL_cur - C);
            pub(&wbuf[((k + 1) & 1) * NTAGS + row],
                (bf16rne(wn) & 0xFFFF0000u) | ((tag + 1u) & 0xFFFFu));
        }
        featL_cur = featL_nxt;
    }

    if (rank == 0 && tid == 0) Ssum[rec] = S;
}

// Serial stitch (rank-1 segment composition): v = y_s + LSE(z_s+v) - LSE(z_s).
__global__ void crf_stitch_k(const uint32_t* __restrict__ wbufs,
                             const double* __restrict__ Ssum,
                             const float* __restrict__ trans,
                             const int* __restrict__ start_p, const int* __restrict__ stop_p,
                             float* __restrict__ fs_out)
{
    const int j = threadIdx.x;   // 1024
    __shared__ float sred[16];

    auto bmax = [&](float x) -> float {
#pragma unroll
        for (int o = 32; o > 0; o >>= 1) x = fmaxf(x, __shfl_xor(x, o));
        if ((j & 63) == 0) sred[j >> 6] = x;
        __syncthreads();
        float m = sred[0];
#pragma unroll
        for (int q = 1; q < 16; ++q) m = fmaxf(m, sred[q]);
        __syncthreads();
        return m;
    };
    auto bsum = [&](float x) -> float {
#pragma unroll
        for (int o = 32; o > 0; o >>= 1) x += __shfl_xor(x, o);
        if ((j & 63) == 0) sred[j >> 6] = x;
        __syncthreads();
        float s = 0.f;
#pragma unroll
        for (int q = 0; q < 16; ++q) s += sred[q];
        __syncthreads();
        return s;
    };

    float v = (j == *start_p) ? 0.0f : -10000.0f;
    for (int s = 0; s < NSEG; ++s) {
        const float yp = __uint_as_float(wbufs[s * 2048 + j] & 0xFFFF0000u);
        const float zp = __uint_as_float(wbufs[(NSEG + s) * 2048 + j] & 0xFFFF0000u);
        const float y = (float)(LN2_D * ((double)__log2f(yp) + Ssum[s]));
        const float z = (float)(LN2_D * ((double)__log2f(zp) + Ssum[NSEG + s]));
        const float m1 = bmax(z + v);
        const float s1 = bsum(__expf(z + v - m1));
        const float m2 = bmax(z);
        const float s2 = bsum(__expf(z - m2));
        v = y + ((m1 + __logf(s1)) - (m2 + __logf(s2)));
    }
    const float tr = trans[(size_t)(*stop_p) * NTAGS + j];
    const float m = bmax(v + tr);
    const float ss = bsum(__expf(v + tr - m));
    if (j == 0) fs_out[0] = m + __logf(ss);
}

__global__ void crf_out_k(const float* __restrict__ fsp, const float* __restrict__ tsum,
                          const float* __restrict__ part, const float* __restrict__ trans,
                          const int* __restrict__ tags, const int* __restrict__ stop_p,
                          float* __restrict__ out) {
    const int j = threadIdx.x; // 1024
    float e = 0.f;
    for (int cc = 0; cc < 16; ++cc) e += part[cc * NTAGS + j];
    const int stop = *stop_p;
    const int last = tags[SEQLEN - 1];
    out[j] = fsp[0] - (tsum[0] + e + trans[(size_t)stop * NTAGS + last]);
}

extern "C" void kernel_launch(void* const* d_in, const int* in_sizes, int n_in,
                              void* d_out, int out_size, void* d_ws, size_t ws_size,
                              hipStream_t stream) {
    const float* feats = (const float*)d_in[0];
    const float* trans = (const float*)d_in[1];
    const int* tags    = (const int*)d_in[2];
    const int* start_p = (const int*)d_in[3];
    const int* stop_p  = (const int*)d_in[4];
    float* out = (float*)d_out;

    char* ws = (char*)d_ws;
    uint32_t* wbufs = (uint32_t*)(ws + 0);
    float* part     = (float*)(ws + 262144);
    double* Ssum    = (double*)(ws + 327680);
    float* fs       = (float*)(ws + 327936);
    float* tsum     = (float*)(ws + 327940);
    int* cnt        = (int*)(ws + 327944);

    (void)hipFuncSetAttribute((const void*)crf_scan_k,
                              hipFuncAttributeMaxDynamicSharedMemorySize, ELDS_BYTES);

    crf_clear_k<<<1, 256, 0, stream>>>(wbufs, cnt);
    crf_emit_k<<<64, 256, 0, stream>>>(feats, tags, part);
    crf_trans_k<<<1, 256, 0, stream>>>(trans, tags, start_p, tsum);
    crf_scan_k<<<NREC * BPR, TPB, ELDS_BYTES, stream>>>(feats, trans, wbufs, cnt, Ssum);
    crf_stitch_k<<<1, 1024, 0, stream>>>(wbufs, Ssum, trans, start_p, stop_p, fs);
    crf_out_k<<<1, 1024, 0, stream>>>(fs, tsum, part, trans, tags, stop_p, out);
}

// Round 9
// 2239.765 us; speedup vs baseline: 5.7113x; 3.8021x over previous
//
#include <hip/hip_runtime.h>
#include <stdint.h>

#define LOG2E_F 1.4426950408889634f
#define LN2_D   0.6931471805599453
#define SEQLEN  16384
#define NTAGS   1024
#define TPB     512
#define NGROUP  32        // 16 fwd + 16 bwd groups
#define GPB     8         // blocks per group
#define ROWS    128       // rows per block
#define FAST_TRIES 300
#define GUARD_MAX 200000
#define ELDS_BYTES 131072 // E: [64][512] u32 fp8x4, column-major per-thread

typedef float f32x2 __attribute__((ext_vector_type(2)));

__device__ __forceinline__ uint32_t bf16rne(float x) {
    uint32_t b = __float_as_uint(x);
    b += 0x7FFFu + ((b >> 16) & 1u);
    return b;
}

#if __has_builtin(__builtin_amdgcn_cvt_pk_fp8_f32) && __has_builtin(__builtin_amdgcn_cvt_pk_f32_fp8)
__device__ __forceinline__ uint32_t pack4_fp8(float x0, float x1, float x2, float x3) {
    int v = __builtin_amdgcn_cvt_pk_fp8_f32(x0, x1, 0, false);
    v = __builtin_amdgcn_cvt_pk_fp8_f32(x2, x3, v, true);
    return (uint32_t)v;
}
#define DEC2LO(u) ((f32x2)__builtin_amdgcn_cvt_pk_f32_fp8((int)(u), false))
#define DEC2HI(u) ((f32x2)__builtin_amdgcn_cvt_pk_f32_fp8((int)(u), true))
#else
__device__ __forceinline__ uint32_t enc1_fp8(float x) {
    if (x >= 448.f) return 0x7Eu;
    if (x < 0.015625f) { int m = (int)(x * 512.f + 0.5f); return (uint32_t)m; }
    uint32_t u = __float_as_uint(x);
    u += 0x7FFFFu + ((u >> 20) & 1u);
    int e32 = (int)(u >> 23) - 127;
    if (e32 > 8) return 0x7Eu;
    return (uint32_t)(((e32 + 7) << 3) | ((u >> 20) & 7u));
}
__device__ __forceinline__ uint32_t pack4_fp8(float x0, float x1, float x2, float x3) {
    return enc1_fp8(x0) | (enc1_fp8(x1) << 8) | (enc1_fp8(x2) << 16) | (enc1_fp8(x3) << 24);
}
__device__ __forceinline__ float dec1_fp8(uint32_t b) {
    b &= 0xFFu;
    uint32_t e = (b >> 3) & 0xFu, m = b & 7u;
    if (e == 0) return (float)m * 0.001953125f;
    return __uint_as_float(((e + 120u) << 23) | (m << 20));
}
__device__ __forceinline__ f32x2 dec2lo_(uint32_t u) { f32x2 r; r.x = dec1_fp8(u); r.y = dec1_fp8(u >> 8); return r; }
__device__ __forceinline__ f32x2 dec2hi_(uint32_t u) { f32x2 r; r.x = dec1_fp8(u >> 16); r.y = dec1_fp8(u >> 24); return r; }
#define DEC2LO(u) dec2lo_(u)
#define DEC2HI(u) dec2hi_(u)
#endif

__global__ void crf_clear_k(uint32_t* __restrict__ wbufs, int nwords) {
    for (int i = blockIdx.x * blockDim.x + threadIdx.x; i < nwords; i += gridDim.x * blockDim.x)
        __hip_atomic_store(&wbufs[i], 0xFFFFu, __ATOMIC_RELAXED, __HIP_MEMORY_SCOPE_AGENT);
}

__global__ void crf_emit_k(const float* __restrict__ feats, const int* __restrict__ tags,
                           float* __restrict__ part) {
    __shared__ int tg[1024];
    const int tid = threadIdx.x;          // 256
    const int b = blockIdx.x;             // 64 blocks: 16 t-chunks x 4 col-chunks
    const int cch = b >> 2;
    const int jb = b & 3;
    for (int q = tid; q < 1024; q += 256) tg[q] = tags[cch * 1024 + q];
    __syncthreads();
    const int j = jb * 256 + tid;
    float acc = 0.f;
#pragma unroll 8
    for (int k = 0; k < 1024; ++k) acc += feats[(size_t)tg[k] * NTAGS + j];
    part[cch * NTAGS + j] = acc;
}

__global__ void crf_trans_k(const float* __restrict__ trans, const int* __restrict__ tags,
                            const int* __restrict__ start_p, float* __restrict__ tsum) {
    __shared__ float red[256];
    const int tid = threadIdx.x;
    const int start = *start_p;
    float acc = 0.f;
    for (int k = 0; k < 64; ++k) {
        const int t = tid * 64 + k;
        const int prev = (t == 0) ? start : tags[t - 1];
        acc += trans[(size_t)tags[t] * NTAGS + prev];
    }
    red[tid] = acc;
    __syncthreads();
    for (int s = 128; s > 0; s >>= 1) { if (tid < s) red[tid] += red[tid + s]; __syncthreads(); }
    if (tid == 0) *tsum = red[0];
}

// K = 16*CPG chunks per direction, L = 1024/CPG steps. Group = 8 blocks (E rows
// split 128 each); each group advances CPG chunk-columns per exchange step.
template <int CPG>
__global__ __launch_bounds__(TPB, 1) void crf_scan_k(
    const float* __restrict__ feats, const float* __restrict__ trans,
    uint32_t* __restrict__ wbufs, double* __restrict__ Ssum)
{
    extern __shared__ uint32_t elds[];          // [64][512] fp8x4, column-major
    __shared__ uint32_t w_lds[8][512];          // bf16-pair packed, f(q)-swizzled
    __shared__ float cmax_lds[8];
    __shared__ int deadf;

    const int tid = threadIdx.x;
    const int g = blockIdx.x >> 3;              // group 0..31
    const int rank = blockIdx.x & 7;
    const int bwd = g >> 4;
    const int gl = g & 15;
    const int L = 1024 / CPG;
    const int row0 = rank * ROWS;
    const int rg = tid >> 4, kc = tid & 15;     // 32 row-groups x 16 k-chunks
    const int pw0 = tid & 63;                   // poller: 16-row chunk
    const int pcol = tid >> 6;                  // poller: column (wave id)
    const bool polls = (pcol < CPG);
    const bool ispub = ((tid & 15) == 0);
    uint32_t* wgrp = wbufs + (size_t)g * (2 * CPG * 1024);

    if (tid == 0) deadf = 0;
    for (int i = tid; i < 8 * 512; i += TPB) ((uint32_t*)w_lds)[i] = 0u;  // no-NaN floor

    // ---- init publish (tag 0, parity 0) BEFORE E staging (reduces skew) ----
    for (int w = tid; w < ROWS * CPG; w += TPB) {
        const int c = w >> 7;
        const int row = w & 127;
        float wn;
        if (!bwd) wn = 1.0f;
        else {
            const int chunk = gl * CPG + c;
            const float f = feats[(size_t)(chunk * L + L - 1) * NTAGS + row0 + row] * LOG2E_F;
            wn = exp2f(f - 10.0f);
        }
        __hip_atomic_store(&wgrp[c * 1024 + row0 + row], bf16rne(wn) & 0xFFFF0000u,
                           __ATOMIC_RELAXED, __HIP_MEMORY_SCOPE_AGENT);
    }

    // ---- stage E chunk (fwd: rows of E; bwd: rows of E^T) as fp8x4 ----
    for (int r = 0; r < 4; ++r) {
        const int grow = row0 + 4 * rg + r;
        for (int q = 0; q < 16; ++q) {
            const int k0 = 64 * kc + 4 * q;
            float x[4];
            for (int j = 0; j < 4; ++j) {
                const float t = bwd ? trans[(size_t)(k0 + j) * NTAGS + grow]
                                    : trans[(size_t)grow * NTAGS + k0 + j];
                x[j] = exp2f(t * LOG2E_F);
            }
            elds[(r * 16 + q) * 512 + tid] = pack4_fp8(x[0], x[1], x[2], x[3]);
        }
    }
    __syncthreads();

    double S[CPG];
#pragma unroll
    for (int c = 0; c < CPG; ++c) S[c] = bwd ? 10.0 : 0.0;

    int fastok = 1;

    for (int tau = 0; tau < L; ++tau) {
        const uint32_t tag = (uint32_t)tau;
        const uint64_t tag2 = (uint64_t)tag | ((uint64_t)tag << 32);

        // feat prefetch for publishers (issued before poll; hidden latency)
        float ff[4][CPG];
        if (ispub) {
#pragma unroll
            for (int c = 0; c < CPG; ++c) {
                int t;
                if (!bwd) t = (gl * CPG + c) * L + tau;
                else t = (tau <= L - 2) ? ((gl * CPG + c) * L + L - 2 - tau) : -1;
#pragma unroll
                for (int r = 0; r < 4; ++r)
                    ff[r][c] = (t >= 0)
                        ? feats[(size_t)t * NTAGS + row0 + 4 * rg + r] * LOG2E_F : 0.f;
            }
        }

        // ---- poll 16 words (one wave per column): sc0-batch fast, agent fallback ----
        if (polls) {
            const uint32_t* pp = wgrp + (tau & 1) * CPG * 1024 + pcol * 1024 + 16 * pw0;
            uint4 A, B, C4, D4;
            int got = 0;
            if (fastok && tau >= 1) {
                for (int it = 0; it < FAST_TRIES; ++it) {
                    asm volatile(
                        "global_load_dwordx4 %0, %4, off sc0 sc1\n\t"
                        "global_load_dwordx4 %1, %5, off sc0 sc1\n\t"
                        "global_load_dwordx4 %2, %6, off sc0 sc1\n\t"
                        "global_load_dwordx4 %3, %7, off sc0 sc1\n\t"
                        "s_waitcnt vmcnt(0)"
                        : "=&v"(A), "=&v"(B), "=&v"(C4), "=&v"(D4)
                        : "v"(pp), "v"(pp + 4), "v"(pp + 8), "v"(pp + 12)
                        : "memory");
                    const uint32_t bad =
                        ((A.x ^ tag) | (A.y ^ tag) | (A.z ^ tag) | (A.w ^ tag) |
                         (B.x ^ tag) | (B.y ^ tag) | (B.z ^ tag) | (B.w ^ tag) |
                         (C4.x ^ tag) | (C4.y ^ tag) | (C4.z ^ tag) | (C4.w ^ tag) |
                         (D4.x ^ tag) | (D4.y ^ tag) | (D4.z ^ tag) | (D4.w ^ tag)) & 0xFFFFu;
                    if (bad == 0u) { got = 1; break; }
                }
                if (!got) fastok = 0;   // sticky: stop paying for a cold path
            }
            if (!got) {   // proven agent-scope protocol (R4-R7)
                int guard = 0;
                for (;;) {
                    uint64_t v[8];
#pragma unroll
                    for (int q = 0; q < 8; ++q)
                        v[q] = __hip_atomic_load((const uint64_t*)(pp + 2 * q),
                                                 __ATOMIC_RELAXED, __HIP_MEMORY_SCOPE_AGENT);
                    uint64_t badl = 0;
#pragma unroll
                    for (int q = 0; q < 8; ++q) badl |= (v[q] ^ tag2);
                    if (((badl | (badl >> 32)) & 0xFFFFull) == 0ull) {
                        A = make_uint4((uint32_t)v[0], (uint32_t)(v[0] >> 32),
                                       (uint32_t)v[1], (uint32_t)(v[1] >> 32));
                        B = make_uint4((uint32_t)v[2], (uint32_t)(v[2] >> 32),
                                       (uint32_t)v[3], (uint32_t)(v[3] >> 32));
                        C4 = make_uint4((uint32_t)v[4], (uint32_t)(v[4] >> 32),
                                        (uint32_t)v[5], (uint32_t)(v[5] >> 32));
                        D4 = make_uint4((uint32_t)v[6], (uint32_t)(v[6] >> 32),
                                        (uint32_t)v[7], (uint32_t)(v[7] >> 32));
                        break;
                    }
                    if (++guard > GUARD_MAX) { deadf = 1; A = B = C4 = D4 = make_uint4(0,0,0,0); break; }
                }
            }
            // pack bf16 pairs (rows 2m,2m+1 -> one u32); involution swizzle f(q)
            const uint32_t o0 = (A.x >> 16) | (A.y & 0xFFFF0000u);
            const uint32_t o1 = (A.z >> 16) | (A.w & 0xFFFF0000u);
            const uint32_t o2 = (B.x >> 16) | (B.y & 0xFFFF0000u);
            const uint32_t o3 = (B.z >> 16) | (B.w & 0xFFFF0000u);
            const uint32_t o4 = (C4.x >> 16) | (C4.y & 0xFFFF0000u);
            const uint32_t o5 = (C4.z >> 16) | (C4.w & 0xFFFF0000u);
            const uint32_t o6 = (D4.x >> 16) | (D4.y & 0xFFFF0000u);
            const uint32_t o7 = (D4.z >> 16) | (D4.w & 0xFFFF0000u);
            const int ub = 8 * pw0;
            const int X = ((pw0 >> 2) & 7) << 2;        // = ((q>>5)&7)<<2 for all 8 pairs
            *(uint2*)&w_lds[pcol][(ub + 0) ^ X] = make_uint2(o0, o1);
            *(uint2*)&w_lds[pcol][(ub + 2) ^ X] = make_uint2(o2, o3);
            *(uint2*)&w_lds[pcol][(ub + 4) ^ X] = make_uint2(o4, o5);
            *(uint2*)&w_lds[pcol][(ub + 6) ^ X] = make_uint2(o6, o7);
            // column max (exact, identical in every block)
            float m = fmaxf(__uint_as_float(o0 << 16), __uint_as_float(o0 & 0xFFFF0000u));
            m = fmaxf(m, fmaxf(__uint_as_float(o1 << 16), __uint_as_float(o1 & 0xFFFF0000u)));
            m = fmaxf(m, fmaxf(__uint_as_float(o2 << 16), __uint_as_float(o2 & 0xFFFF0000u)));
            m = fmaxf(m, fmaxf(__uint_as_float(o3 << 16), __uint_as_float(o3 & 0xFFFF0000u)));
            m = fmaxf(m, fmaxf(__uint_as_float(o4 << 16), __uint_as_float(o4 & 0xFFFF0000u)));
            m = fmaxf(m, fmaxf(__uint_as_float(o5 << 16), __uint_as_float(o5 & 0xFFFF0000u)));
            m = fmaxf(m, fmaxf(__uint_as_float(o6 << 16), __uint_as_float(o6 & 0xFFFF0000u)));
            m = fmaxf(m, fmaxf(__uint_as_float(o7 << 16), __uint_as_float(o7 & 0xFFFF0000u)));
#pragma unroll
            for (int o = 32; o > 0; o >>= 1) m = fmaxf(m, __shfl_xor(m, o));
            if ((tid & 63) == 0) cmax_lds[pcol] = m;
        }
        __syncthreads();              // B1: w_lds + cmax ready; deadf visible
        if (deadf) break;

        float Cc[CPG];
#pragma unroll
        for (int c = 0; c < CPG; ++c) Cc[c] = __log2f(cmax_lds[c]) + 10.0f;
        if (tid == 0) {
#pragma unroll
            for (int c = 0; c < CPG; ++c) S[c] += (double)Cc[c];
        }

        // ---- compute: acc[r][c] = sum_k E[4rg+r, 64kc+k] * w[64kc+k, c] ----
        float acc[4][CPG];
#pragma unroll
        for (int r = 0; r < 4; ++r)
#pragma unroll
            for (int c = 0; c < CPG; ++c) acc[r][c] = 0.f;

#pragma unroll
        for (int kq = 0; kq < 16; ++kq) {
            float e[4][4];
#pragma unroll
            for (int r = 0; r < 4; ++r) {
                const uint32_t ev = elds[(r * 16 + kq) * 512 + tid];
                const f32x2 lo = DEC2LO(ev), hi = DEC2HI(ev);
                e[r][0] = lo.x; e[r][1] = lo.y; e[r][2] = hi.x; e[r][3] = hi.y;
            }
            const int u = 32 * kc + 2 * kq;
            const int pu = u ^ ((kc & 7) << 2);        // = f(u): matches writer
#pragma unroll
            for (int c = 0; c < CPG; ++c) {
                const uint2 wp = *(const uint2*)&w_lds[c][pu];
                const float w0 = __uint_as_float(wp.x << 16);
                const float w1 = __uint_as_float(wp.x & 0xFFFF0000u);
                const float w2 = __uint_as_float(wp.y << 16);
                const float w3 = __uint_as_float(wp.y & 0xFFFF0000u);
#pragma unroll
                for (int r = 0; r < 4; ++r)
                    acc[r][c] = fmaf(e[r][0], w0, fmaf(e[r][1], w1,
                                fmaf(e[r][2], w2, fmaf(e[r][3], w3, acc[r][c]))));
            }
        }
        // reduce across the 16 kc lanes
#pragma unroll
        for (int r = 0; r < 4; ++r)
#pragma unroll
            for (int c = 0; c < CPG; ++c) {
                float v = acc[r][c];
                v += __shfl_xor(v, 1); v += __shfl_xor(v, 2);
                v += __shfl_xor(v, 4); v += __shfl_xor(v, 8);
                acc[r][c] = v;
            }

        // ---- publish (kc==0 lanes): apply D-scale and normalization ----
        if (ispub) {
            uint32_t* pub = wgrp + ((tau + 1) & 1) * CPG * 1024;
#pragma unroll
            for (int c = 0; c < CPG; ++c)
#pragma unroll
                for (int r = 0; r < 4; ++r) {
                    const float wn = acc[r][c] * exp2f(ff[r][c] - Cc[c]);
                    __hip_atomic_store(&pub[c * 1024 + row0 + 4 * rg + r],
                                       (bf16rne(wn) & 0xFFFF0000u) | ((tag + 1u) & 0xFFFFu),
                                       __ATOMIC_RELAXED, __HIP_MEMORY_SCOPE_AGENT);
                }
        }
        __syncthreads();              // B2: compute/publish done before next w_lds write
    }

    if (rank == 0 && tid == 0) {
        const int K = 16 * CPG;
        for (int c = 0; c < CPG; ++c)
            Ssum[bwd * K + gl * CPG + c] = S[c];
    }
}

// Per-chunk reductions: sumy[c] = sum(y_c); dot[c] = z_c . y_{c-1} (c>=1);
// dot[0] = z_0[start]; fin = sum_j y_{K-1,j} * e^{T[stop,j]}.
__global__ void crf_dots_k(const uint32_t* __restrict__ wbufs, const float* __restrict__ trans,
                           const int* __restrict__ start_p, const int* __restrict__ stop_p,
                           double* __restrict__ dotv, double* __restrict__ sumyv,
                           double* __restrict__ finv, int K, int CPG)
{
    const int c = blockIdx.x;
    const int tid = threadIdx.x;   // 256
    __shared__ double red[256];
    const uint32_t* y   = wbufs + ((size_t)((c / CPG) * 2) * CPG + (c % CPG)) * 1024;
    const uint32_t* z   = wbufs + ((size_t)((16 + c / CPG) * 2) * CPG + (c % CPG)) * 1024;
    const uint32_t* ym1 = (c > 0)
        ? wbufs + ((size_t)(((c - 1) / CPG) * 2) * CPG + ((c - 1) % CPG)) * 1024 : nullptr;
    const int stop = *stop_p;

    double sy = 0, dt = 0, fn = 0;
    for (int j = tid; j < 1024; j += 256) {
        const double yv = (double)__uint_as_float(y[j] & 0xFFFF0000u);
        sy += yv;
        if (c > 0) dt += (double)__uint_as_float(z[j] & 0xFFFF0000u) *
                         (double)__uint_as_float(ym1[j] & 0xFFFF0000u);
        if (c == K - 1) fn += yv * (double)__expf(trans[(size_t)stop * NTAGS + j]);
    }
    red[tid] = sy; __syncthreads();
    for (int s = 128; s > 0; s >>= 1) { if (tid < s) red[tid] += red[tid + s]; __syncthreads(); }
    if (tid == 0) sumyv[c] = red[0];
    __syncthreads();
    red[tid] = dt; __syncthreads();
    for (int s = 128; s > 0; s >>= 1) { if (tid < s) red[tid] += red[tid + s]; __syncthreads(); }
    if (tid == 0 && c > 0) dotv[c] = red[0];
    __syncthreads();
    red[tid] = fn; __syncthreads();
    for (int s = 128; s > 0; s >>= 1) { if (tid < s) red[tid] += red[tid + s]; __syncthreads(); }
    if (tid == 0 && c == K - 1) finv[0] = red[0];
    if (tid == 0 && c == 0)
        dotv[0] = (double)__uint_as_float(z[*start_p] & 0xFFFF0000u);
}

__global__ void crf_fs_k(const double* __restrict__ Ssum, const double* __restrict__ dotv,
                         const double* __restrict__ sumyv, const double* __restrict__ finv,
                         float* __restrict__ fs_out, int K)
{
    if (threadIdx.x == 0) {
        double acc = 0.0;
        acc += log2(dotv[0]) + Ssum[K];          // z_0[start], scale Sz_0
        acc -= log2(sumyv[0]) + Ssum[0];         // - log2 s_0
        for (int c = 1; c < K; ++c)
            acc += log2(dotv[c]) + Ssum[K + c] + Ssum[c - 1]
                 - log2(sumyv[c]) - Ssum[c];
        acc += log2(finv[0]) + Ssum[K - 1];
        fs_out[0] = (float)(LN2_D * acc);
    }
}

__global__ void crf_out_k(const float* __restrict__ fsp, const float* __restrict__ tsum,
                          const float* __restrict__ part, const float* __restrict__ trans,
                          const int* __restrict__ tags, const int* __restrict__ stop_p,
                          float* __restrict__ out) {
    const int j = threadIdx.x; // 1024
    float e = 0.f;
    for (int cc = 0; cc < 16; ++cc) e += part[cc * NTAGS + j];
    const int stop = *stop_p;
    const int last = tags[SEQLEN - 1];
    out[j] = fsp[0] - (tsum[0] + e + trans[(size_t)stop * NTAGS + last]);
}

extern "C" void kernel_launch(void* const* d_in, const int* in_sizes, int n_in,
                              void* d_out, int out_size, void* d_ws, size_t ws_size,
                              hipStream_t stream) {
    const float* feats = (const float*)d_in[0];
    const float* trans = (const float*)d_in[1];
    const int* tags    = (const int*)d_in[2];
    const int* start_p = (const int*)d_in[3];
    const int* stop_p  = (const int*)d_in[4];
    float* out = (float*)d_out;

    // pick CPG by available workspace: WB = 262144*CPG + ~72KB aux
    int CPG = 1;
    if (ws_size >= 262144ull * 8 + 73728) CPG = 8;
    else if (ws_size >= 262144ull * 4 + 73728) CPG = 4;
    const int K = 16 * CPG;
    const size_t WB = 262144ull * CPG;

    char* ws = (char*)d_ws;
    uint32_t* wbufs = (uint32_t*)(ws + 0);
    float* part     = (float*)(ws + WB);
    double* Ssum    = (double*)(ws + WB + 65536);
    double* dotv    = (double*)(ws + WB + 65536 + 2048);
    double* sumyv   = (double*)(ws + WB + 65536 + 4096);
    double* finv    = (double*)(ws + WB + 65536 + 6144);
    float* fs       = (float*)(ws + WB + 65536 + 6152);
    float* tsum     = (float*)(ws + WB + 65536 + 6156);

    crf_clear_k<<<256, 256, 0, stream>>>(wbufs, NGROUP * 2 * CPG * 1024);
    crf_emit_k<<<64, 256, 0, stream>>>(feats, tags, part);
    crf_trans_k<<<1, 256, 0, stream>>>(trans, tags, start_p, tsum);

    if (CPG == 8) {
        (void)hipFuncSetAttribute((const void*)crf_scan_k<8>,
                                  hipFuncAttributeMaxDynamicSharedMemorySize, ELDS_BYTES);
        crf_scan_k<8><<<NGROUP * GPB, TPB, ELDS_BYTES, stream>>>(feats, trans, wbufs, Ssum);
    } else if (CPG == 4) {
        (void)hipFuncSetAttribute((const void*)crf_scan_k<4>,
                                  hipFuncAttributeMaxDynamicSharedMemorySize, ELDS_BYTES);
        crf_scan_k<4><<<NGROUP * GPB, TPB, ELDS_BYTES, stream>>>(feats, trans, wbufs, Ssum);
    } else {
        (void)hipFuncSetAttribute((const void*)crf_scan_k<1>,
                                  hipFuncAttributeMaxDynamicSharedMemorySize, ELDS_BYTES);
        crf_scan_k<1><<<NGROUP * GPB, TPB, ELDS_BYTES, stream>>>(feats, trans, wbufs, Ssum);
    }

    crf_dots_k<<<K, 256, 0, stream>>>(wbufs, trans, start_p, stop_p, dotv, sumyv, finv, K, CPG);
    crf_fs_k<<<1, 64, 0, stream>>>(Ssum, dotv, sumyv, finv, fs, K);
    crf_out_k<<<1, 1024, 0, stream>>>(fs, tsum, part, trans, tags, stop_p, out);
}

// Round 10
// 937.802 us; speedup vs baseline: 13.6404x; 2.3883x over previous
//
#include <hip/hip_runtime.h>
#include <stdint.h>

#define LOG2E_F 1.4426950408889634f
#define LN2_D   0.6931471805599453
#define SEQLEN  16384
#define NTAGS   1024
#define TPB     512
#define NGROUP  32        // 16 fwd + 16 bwd groups
#define GPB     8
#define ROWS    128
#define CPG     16        // chunk-columns per group = MFMA N
#define LSEG    64        // steps per chunk
#define KCH     256       // chunks per direction
#define COFF    13.0f
#define GUARD_MAX 50000
#define GRPW    16384     // words per group: 2 parity x 16 col x 512

typedef float f32x2 __attribute__((ext_vector_type(2)));
typedef float f32x4 __attribute__((ext_vector_type(4)));
typedef uint32_t u32;
typedef uint64_t u64;

#define REP4(M, B)   M(B) M((B)+1) M((B)+2) M((B)+3)
#define REP16(M, B)  REP4(M, B) REP4(M, (B)+4) REP4(M, (B)+8) REP4(M, (B)+12)
#define REP32(M, B)  REP16(M, B) REP16(M, (B)+16)

#if __has_builtin(__builtin_amdgcn_cvt_pk_fp8_f32) && __has_builtin(__builtin_amdgcn_cvt_pk_f32_fp8)
__device__ __forceinline__ u32 pack4_fp8(float x0, float x1, float x2, float x3) {
    int v = __builtin_amdgcn_cvt_pk_fp8_f32(x0, x1, 0, false);
    v = __builtin_amdgcn_cvt_pk_fp8_f32(x2, x3, v, true);
    return (u32)v;
}
__device__ __forceinline__ float dec8(u32 b) {
    f32x2 r = (f32x2)__builtin_amdgcn_cvt_pk_f32_fp8((int)(b & 0xFFu), false);
    return r.x;
}
#else
__device__ __forceinline__ u32 enc1_fp8(float x) {
    if (x >= 448.f) return 0x7Eu;
    if (x < 0.015625f) { int m = (int)(x * 512.f + 0.5f); return (u32)m; }
    u32 u = __float_as_uint(x);
    u += 0x7FFFFu + ((u >> 20) & 1u);
    int e32 = (int)(u >> 23) - 127;
    if (e32 > 8) return 0x7Eu;
    return (u32)(((e32 + 7) << 3) | ((u >> 20) & 7u));
}
__device__ __forceinline__ u32 pack4_fp8(float x0, float x1, float x2, float x3) {
    return enc1_fp8(x0) | (enc1_fp8(x1) << 8) | (enc1_fp8(x2) << 16) | (enc1_fp8(x3) << 24);
}
__device__ __forceinline__ float dec8(u32 b) {
    b &= 0xFFu;
    u32 e = (b >> 3) & 0xFu, m = b & 7u;
    if (e == 0) return (float)m * 0.001953125f;
    return __uint_as_float(((e + 120u) << 23) | (m << 20));
}
#endif

__global__ void crf_clear_k(u32* __restrict__ wbufs, int nwords) {
    for (int i = blockIdx.x * blockDim.x + threadIdx.x; i < nwords; i += gridDim.x * blockDim.x)
        __hip_atomic_store(&wbufs[i], 0xFFFFu, __ATOMIC_RELAXED, __HIP_MEMORY_SCOPE_AGENT);
}

__global__ void crf_emit_k(const float* __restrict__ feats, const int* __restrict__ tags,
                           float* __restrict__ part) {
    __shared__ int tg[2048];
    const int tid = threadIdx.x;          // 256
    const int b = blockIdx.x;             // 32 blocks: 8 t-chunks x 4 col-chunks
    const int cch = b >> 2, jb = b & 3;
    for (int q = tid; q < 2048; q += 256) tg[q] = tags[cch * 2048 + q];
    __syncthreads();
    const int j = jb * 256 + tid;
    float acc = 0.f;
#pragma unroll 8
    for (int k = 0; k < 2048; ++k) acc += feats[(size_t)tg[k] * NTAGS + j];
    part[cch * NTAGS + j] = acc;
}

__global__ void crf_trans_k(const float* __restrict__ trans, const int* __restrict__ tags,
                            const int* __restrict__ start_p, float* __restrict__ tsum) {
    __shared__ float red[256];
    const int tid = threadIdx.x;
    const int start = *start_p;
    float acc = 0.f;
    for (int k = 0; k < 64; ++k) {
        const int t = tid * 64 + k;
        const int prev = (t == 0) ? start : tags[t - 1];
        acc += trans[(size_t)tags[t] * NTAGS + prev];
    }
    red[tid] = acc;
    __syncthreads();
    for (int s = 128; s > 0; s >>= 1) { if (tid < s) red[tid] += red[tid + s]; __syncthreads(); }
    if (tid == 0) *tsum = red[0];
}

__global__ __launch_bounds__(TPB, 1) void crf_scan_k(
    const float* __restrict__ feats, const float* __restrict__ trans,
    u32* __restrict__ wbufs, double* __restrict__ Ssum)
{
    __shared__ uint2 wBf[2][32][64];     // MFMA-slot B fragments, double-buffered
    __shared__ u32 cmaxb[2][16];
    __shared__ double Sl[16];
    __shared__ float fbx[8][16][17];     // fallback transpose buffer
    __shared__ int okf, deadf;

    const int tid = threadIdx.x;
    const int l = tid & 63, wv = tid >> 6;
    const int g = blockIdx.x >> 3, rank = blockIdx.x & 7;
    const int bwd = g >> 4, gl = g & 15;
    const int row0 = rank * ROWS;
    const int pc = tid >> 5, pa = tid & 31;    // poller: col, k-chunk
    const int myc = l & 15, h = l >> 4;
    const int growA = row0 + wv * 16 + myc;    // A-fragment row
    const int growD = row0 + wv * 16 + h * 4;  // D first row (4 consecutive)
    u32* wgrp = wbufs + (size_t)g * GRPW;

    if (tid == 0) {
        okf = 1; deadf = 0;
#pragma unroll
        for (int c = 0; c < 16; ++c) Sl[c] = bwd ? 3.0 : 0.0;
    }

    // ---- init publish (tag 0, parity 0): fwd ones; bwd exp2(ff_last - 3) ----
#pragma unroll
    for (int s = 0; s < 2; ++s) {
        const int f = tid * 2 + s;            // 0..1023
        const int c = f >> 6, q = f & 63;
        u32 b0, b1;
        if (!bwd) { b0 = b1 = 0x38u; }        // fp8(1.0)
        else {
            const int t = (gl * CPG + c) * LSEG + LSEG - 1;
            const int j0 = row0 + 2 * q;
            const float f0 = feats[(size_t)t * NTAGS + j0]     * LOG2E_F - 3.0f;
            const float f1 = feats[(size_t)t * NTAGS + j0 + 1] * LOG2E_F - 3.0f;
            const u32 pk = pack4_fp8(exp2f(f0), exp2f(f1), 0.f, 0.f);
            b0 = pk & 0xFFu; b1 = (pk >> 8) & 0xFFu;
        }
        __hip_atomic_store(&wgrp[c * 512 + (row0 >> 1) + q], (b1 << 24) | (b0 << 16),
                           __ATOMIC_RELAXED, __HIP_MEMORY_SCOPE_AGENT);
    }

    // ---- stage E as persistent A-fragments (fp8, 64 VGPR) ----
    // A[row=l&15][k = kk*32 + h*8 + i]; fwd E[row][k]=exp(T[row][k]); bwd exp(T[k][row])
    u64 afr[32];
#define STG(KK) { \
        const int kb = (KK) * 32 + h * 8; \
        float x0,x1,x2,x3,x4,x5,x6,x7; \
        if (!bwd) { \
            const float4 t0 = *(const float4*)&trans[(size_t)growA * NTAGS + kb]; \
            const float4 t1 = *(const float4*)&trans[(size_t)growA * NTAGS + kb + 4]; \
            x0=t0.x; x1=t0.y; x2=t0.z; x3=t0.w; x4=t1.x; x5=t1.y; x6=t1.z; x7=t1.w; \
        } else { \
            x0 = trans[(size_t)(kb+0)*NTAGS + growA]; x1 = trans[(size_t)(kb+1)*NTAGS + growA]; \
            x2 = trans[(size_t)(kb+2)*NTAGS + growA]; x3 = trans[(size_t)(kb+3)*NTAGS + growA]; \
            x4 = trans[(size_t)(kb+4)*NTAGS + growA]; x5 = trans[(size_t)(kb+5)*NTAGS + growA]; \
            x6 = trans[(size_t)(kb+6)*NTAGS + growA]; x7 = trans[(size_t)(kb+7)*NTAGS + growA]; \
        } \
        const u32 lo = pack4_fp8(exp2f(x0*LOG2E_F), exp2f(x1*LOG2E_F), exp2f(x2*LOG2E_F), exp2f(x3*LOG2E_F)); \
        const u32 hi = pack4_fp8(exp2f(x4*LOG2E_F), exp2f(x5*LOG2E_F), exp2f(x6*LOG2E_F), exp2f(x7*LOG2E_F)); \
        afr[KK] = (u64)lo | ((u64)hi << 32); }
    REP32(STG, 0)
#undef STG

    // ---- MFMA layout self-check (exact small-int test; asymmetric) ----
    {
        float av0,av1,av2,av3,av4,av5,av6,av7, bv0,bv1,bv2,bv3,bv4,bv5,bv6,bv7;
#define TV(I) { const int k = h*8 + (I); \
        const float a_ = (float)((myc + k) & 3); \
        const float b_ = (float)(((k ^ myc) & 3) + 1); \
        if ((I)==0){av0=a_;bv0=b_;} if ((I)==1){av1=a_;bv1=b_;} \
        if ((I)==2){av2=a_;bv2=b_;} if ((I)==3){av3=a_;bv3=b_;} \
        if ((I)==4){av4=a_;bv4=b_;} if ((I)==5){av5=a_;bv5=b_;} \
        if ((I)==6){av6=a_;bv6=b_;} if ((I)==7){av7=a_;bv7=b_;} }
        TV(0) TV(1) TV(2) TV(3) TV(4) TV(5) TV(6) TV(7)
#undef TV
        const u64 at = (u64)pack4_fp8(av0,av1,av2,av3) | ((u64)pack4_fp8(av4,av5,av6,av7) << 32);
        const u64 bt = (u64)pack4_fp8(bv0,bv1,bv2,bv3) | ((u64)pack4_fp8(bv4,bv5,bv6,bv7) << 32);
        f32x4 dz = {0.f, 0.f, 0.f, 0.f};
        dz = __builtin_amdgcn_mfma_f32_16x16x32_fp8_fp8((long)at, (long)bt, dz, 0, 0, 0);
        bool good = true;
#pragma unroll
        for (int v = 0; v < 4; ++v) {
            const int row = h * 4 + v;
            float e = 0.f;
            for (int k = 0; k < 32; ++k)
                e += (float)(((row + k) & 3) * (((k ^ myc) & 3) + 1));
            good = good && (dz[v] == e);
        }
        if (!good) okf = 0;
    }
    __syncthreads();
    const bool fb = (okf == 0);

    for (int tau = 0; tau < LSEG; ++tau) {
        const int p = tau & 1;
        const u32 tag = (u32)tau;
        const u64 tag2 = ((u64)tag << 32) | tag;

        // feat prefetch for publish (float4: 4 consecutive D-rows, one col)
        float4 ff4 = make_float4(0.f, 0.f, 0.f, 0.f);
        {
            const int chunk = gl * CPG + myc;
            int t = -1;
            if (!bwd) t = chunk * LSEG + tau;
            else if (tau <= LSEG - 2) t = chunk * LSEG + (LSEG - 2 - tau);
            if (t >= 0) ff4 = *(const float4*)&feats[(size_t)t * NTAGS + growD];
        }

        // ---- poll 16 wire words (col pc, k 32*pa..+31), assemble fp8 u32s ----
        u32 uu0,uu1,uu2,uu3,uu4,uu5,uu6,uu7;
        {
            const u32* pp = wgrp + p * 8192 + pc * 512 + pa * 16;
            int guard = 0;
            for (;;) {
                u64 v0,v1,v2,v3,v4,v5,v6,v7;
                v0 = __hip_atomic_load((const u64*)(pp+ 0), __ATOMIC_RELAXED, __HIP_MEMORY_SCOPE_AGENT);
                v1 = __hip_atomic_load((const u64*)(pp+ 2), __ATOMIC_RELAXED, __HIP_MEMORY_SCOPE_AGENT);
                v2 = __hip_atomic_load((const u64*)(pp+ 4), __ATOMIC_RELAXED, __HIP_MEMORY_SCOPE_AGENT);
                v3 = __hip_atomic_load((const u64*)(pp+ 6), __ATOMIC_RELAXED, __HIP_MEMORY_SCOPE_AGENT);
                v4 = __hip_atomic_load((const u64*)(pp+ 8), __ATOMIC_RELAXED, __HIP_MEMORY_SCOPE_AGENT);
                v5 = __hip_atomic_load((const u64*)(pp+10), __ATOMIC_RELAXED, __HIP_MEMORY_SCOPE_AGENT);
                v6 = __hip_atomic_load((const u64*)(pp+12), __ATOMIC_RELAXED, __HIP_MEMORY_SCOPE_AGENT);
                v7 = __hip_atomic_load((const u64*)(pp+14), __ATOMIC_RELAXED, __HIP_MEMORY_SCOPE_AGENT);
                u64 bad = (v0^tag2)|(v1^tag2)|(v2^tag2)|(v3^tag2)|(v4^tag2)|(v5^tag2)|(v6^tag2)|(v7^tag2);
                if (((bad | (bad >> 32)) & 0xFFFFull) == 0ull) {
                    uu0 = ((u32)v0 >> 16) | ((u32)(v0>>32) & 0xFFFF0000u);
                    uu1 = ((u32)v1 >> 16) | ((u32)(v1>>32) & 0xFFFF0000u);
                    uu2 = ((u32)v2 >> 16) | ((u32)(v2>>32) & 0xFFFF0000u);
                    uu3 = ((u32)v3 >> 16) | ((u32)(v3>>32) & 0xFFFF0000u);
                    uu4 = ((u32)v4 >> 16) | ((u32)(v4>>32) & 0xFFFF0000u);
                    uu5 = ((u32)v5 >> 16) | ((u32)(v5>>32) & 0xFFFF0000u);
                    uu6 = ((u32)v6 >> 16) | ((u32)(v6>>32) & 0xFFFF0000u);
                    uu7 = ((u32)v7 >> 16) | ((u32)(v7>>32) & 0xFFFF0000u);
                    break;
                }
                if (++guard > GUARD_MAX) {
                    deadf = 1; uu0=uu1=uu2=uu3=uu4=uu5=uu6=uu7=0; break;
                }
            }
        }
        // write MFMA B-fragment slots: wBf[p][kk=pa][h*16 + col=pc]
        wBf[p][pa][ 0 + pc] = make_uint2(uu0, uu1);
        wBf[p][pa][16 + pc] = make_uint2(uu2, uu3);
        wBf[p][pa][32 + pc] = make_uint2(uu4, uu5);
        wBf[p][pa][48 + pc] = make_uint2(uu6, uu7);
        // column byte-max (fp8 e4m3 positive: integer order = value order)
        {
            u32 bm = 0;
#define BM(U) { bm = max(bm, (U) & 0xFFu); bm = max(bm, ((U)>>8) & 0xFFu); \
                bm = max(bm, ((U)>>16) & 0xFFu); bm = max(bm, (U)>>24); }
            BM(uu0) BM(uu1) BM(uu2) BM(uu3) BM(uu4) BM(uu5) BM(uu6) BM(uu7)
#undef BM
#pragma unroll
            for (int o = 16; o > 0; o >>= 1) bm = max(bm, (u32)__shfl_xor((int)bm, o));
            if (pa == 0) cmaxb[p][pc] = bm;
        }
        __syncthreads();                 // B1: fragments + cmax ready
        if (deadf) break;

        const float Cme = __log2f(dec8(cmaxb[p][myc])) + COFF;
        if (tid == 0) {
#pragma unroll
            for (int c = 0; c < 16; ++c)
                Sl[c] += (double)(__log2f(dec8(cmaxb[p][c])) + COFF);
        }

        // ---- compute D = E(128x1024) x w(1024x16), this wave's 16-row tile ----
        f32x4 acc;
        if (!fb) {
            f32x4 a0 = {0.f,0.f,0.f,0.f}, a1 = {0.f,0.f,0.f,0.f};
            const uint2* wb = &wBf[p][0][0];
#define MF(KK) { const uint2 bfr = wb[(KK)*64 + l]; \
                 const u64 bb = (u64)bfr.x | ((u64)bfr.y << 32); \
                 if ((KK) & 1) a1 = __builtin_amdgcn_mfma_f32_16x16x32_fp8_fp8((long)afr[KK], (long)bb, a1, 0,0,0); \
                 else          a0 = __builtin_amdgcn_mfma_f32_16x16x32_fp8_fp8((long)afr[KK], (long)bb, a0, 0,0,0); }
            REP32(MF, 0)
#undef MF
            acc = a0 + a1;
        } else {
            // correct-by-construction VALU fallback (layout-assumption-free)
            float a16[16];
#pragma unroll
            for (int c = 0; c < 16; ++c) a16[c] = 0.f;
            const uint2* wb = &wBf[p][0][0];
            for (int kk = 0; kk < 32; ++kk) {
                const u64 av = afr[kk];
                float ea0 = dec8((u32)av), ea1 = dec8((u32)(av>>8)), ea2 = dec8((u32)(av>>16)), ea3 = dec8((u32)(av>>24));
                float ea4 = dec8((u32)(av>>32)), ea5 = dec8((u32)(av>>40)), ea6 = dec8((u32)(av>>48)), ea7 = dec8((u32)(av>>56));
#pragma unroll
                for (int c = 0; c < 16; ++c) {
                    const uint2 bfr = wb[kk*64 + h*16 + c];
                    const u64 bv = (u64)bfr.x | ((u64)bfr.y << 32);
                    float s = fmaf(ea0, dec8((u32)bv), 0.f);
                    s = fmaf(ea1, dec8((u32)(bv>>8)), s);  s = fmaf(ea2, dec8((u32)(bv>>16)), s);
                    s = fmaf(ea3, dec8((u32)(bv>>24)), s); s = fmaf(ea4, dec8((u32)(bv>>32)), s);
                    s = fmaf(ea5, dec8((u32)(bv>>40)), s); s = fmaf(ea6, dec8((u32)(bv>>48)), s);
                    s = fmaf(ea7, dec8((u32)(bv>>56)), s);
                    a16[c] += s;
                }
            }
#pragma unroll
            for (int c = 0; c < 16; ++c) {
                float v2 = a16[c];
                v2 += __shfl_xor(v2, 16); v2 += __shfl_xor(v2, 32);
                a16[c] = v2;
            }
            if (h == 0) {
#pragma unroll
                for (int c = 0; c < 16; ++c) fbx[wv][myc][c] = a16[c];
            }
            __syncthreads();
            acc.x = fbx[wv][h*4+0][myc]; acc.y = fbx[wv][h*4+1][myc];
            acc.z = fbx[wv][h*4+2][myc]; acc.w = fbx[wv][h*4+3][myc];
        }

        // ---- publish tag tau+1 (parity p^1): 4 rows x 1 col -> 2 packed words ----
        {
            const u32 ntag = tag + 1u;
            u32* pub = wgrp + (p ^ 1) * 8192 + myc * 512 + (growD >> 1);
            const float w0 = acc.x * exp2f(fmaf(ff4.x, LOG2E_F, -Cme));
            const float w1 = acc.y * exp2f(fmaf(ff4.y, LOG2E_F, -Cme));
            const float w2 = acc.z * exp2f(fmaf(ff4.z, LOG2E_F, -Cme));
            const float w3 = acc.w * exp2f(fmaf(ff4.w, LOG2E_F, -Cme));
            const u32 pk = pack4_fp8(w0, w1, w2, w3);
            __hip_atomic_store(&pub[0], ((pk & 0xFFFFu) << 16) | ntag,
                               __ATOMIC_RELAXED, __HIP_MEMORY_SCOPE_AGENT);
            __hip_atomic_store(&pub[1], (pk & 0xFFFF0000u) | ntag,
                               __ATOMIC_RELAXED, __HIP_MEMORY_SCOPE_AGENT);
        }
    }

    if (rank == 0 && tid == 0) {
#pragma unroll
        for (int c = 0; c < 16; ++c)
            Ssum[bwd * KCH + gl * CPG + c] = Sl[c];
    }
}

// sumy[c] = 1'y_c ; dot[c] = z_c . y_{c-1} (c>0), dot[0] = z_0[start];
// fin = y_{K-1} . exp(T[stop,:])
__global__ void crf_dots_k(const u32* __restrict__ wbufs, const float* __restrict__ trans,
                           const int* __restrict__ start_p, const int* __restrict__ stop_p,
                           double* __restrict__ dotv, double* __restrict__ sumyv,
                           double* __restrict__ finv)
{
    const int c = blockIdx.x;        // 0..255
    const int tid = threadIdx.x;     // 256
    __shared__ double red[256];
    const int gl = c >> 4, cl = c & 15;
    const u32* y = wbufs + (size_t)gl * GRPW + cl * 512;
    const u32* z = wbufs + (size_t)(16 + gl) * GRPW + cl * 512;
    const int cm = c - 1;
    const u32* ym1 = (c > 0) ? (wbufs + (size_t)(cm >> 4) * GRPW + (cm & 15) * 512) : nullptr;
    const int stop = *stop_p;

    double sy = 0, dt = 0, fn = 0;
    for (int jp = tid; jp < 512; jp += 256) {
        const u32 wy = y[jp];
        const double y0 = (double)dec8((wy >> 16) & 0xFFu), y1 = (double)dec8(wy >> 24);
        sy += y0 + y1;
        if (c > 0) {
            const u32 wz = z[jp], wm = ym1[jp];
            dt += (double)dec8((wz >> 16) & 0xFFu) * (double)dec8((wm >> 16) & 0xFFu)
                + (double)dec8(wz >> 24) * (double)dec8(wm >> 24);
        }
        if (c == KCH - 1)
            fn += y0 * (double)__expf(trans[(size_t)stop * NTAGS + 2*jp])
                + y1 * (double)__expf(trans[(size_t)stop * NTAGS + 2*jp + 1]);
    }
    red[tid] = sy; __syncthreads();
    for (int s = 128; s > 0; s >>= 1) { if (tid < s) red[tid] += red[tid + s]; __syncthreads(); }
    if (tid == 0) sumyv[c] = red[0];
    __syncthreads();
    red[tid] = dt; __syncthreads();
    for (int s = 128; s > 0; s >>= 1) { if (tid < s) red[tid] += red[tid + s]; __syncthreads(); }
    if (tid == 0 && c > 0) dotv[c] = red[0];
    __syncthreads();
    red[tid] = fn; __syncthreads();
    for (int s = 128; s > 0; s >>= 1) { if (tid < s) red[tid] += red[tid + s]; __syncthreads(); }
    if (tid == 0 && c == KCH - 1) finv[0] = red[0];
    if (tid == 0 && c == 0) {
        const int st = *start_p;
        const u32 wz = z[st >> 1];
        dotv[0] = (double)dec8((st & 1) ? (wz >> 24) : ((wz >> 16) & 0xFFu));
    }
}

__global__ void crf_fs_k(const double* __restrict__ Ssum, const double* __restrict__ dotv,
                         const double* __restrict__ sumyv, const double* __restrict__ finv,
                         float* __restrict__ fs_out)
{
    if (threadIdx.x == 0) {
        double acc = 0.0;
        acc += log2(dotv[0]) + Ssum[KCH];
        acc -= log2(sumyv[0]) + Ssum[0];
        for (int c = 1; c < KCH; ++c)
            acc += log2(dotv[c]) + Ssum[KCH + c] + Ssum[c - 1]
                 - log2(sumyv[c]) - Ssum[c];
        acc += log2(finv[0]) + Ssum[KCH - 1];
        fs_out[0] = (float)(LN2_D * acc);
    }
}

__global__ void crf_out_k(const float* __restrict__ fsp, const float* __restrict__ tsum,
                          const float* __restrict__ part, const float* __restrict__ trans,
                          const int* __restrict__ tags, const int* __restrict__ stop_p,
                          float* __restrict__ out) {
    const int j = threadIdx.x; // 1024
    float e = 0.f;
    for (int cc = 0; cc < 8; ++cc) e += part[cc * NTAGS + j];
    const int stop = *stop_p;
    const int last = tags[SEQLEN - 1];
    out[j] = fsp[0] - (tsum[0] + e + trans[(size_t)stop * NTAGS + last]);
}

extern "C" void kernel_launch(void* const* d_in, const int* in_sizes, int n_in,
                              void* d_out, int out_size, void* d_ws, size_t ws_size,
                              hipStream_t stream) {
    const float* feats = (const float*)d_in[0];
    const float* trans = (const float*)d_in[1];
    const int* tags    = (const int*)d_in[2];
    const int* start_p = (const int*)d_in[3];
    const int* stop_p  = (const int*)d_in[4];
    float* out = (float*)d_out;

    // ws: wbufs 2MB | part 32KB | Ssum 4KB | dotv 2KB | sumyv 2KB | finv/fs/tsum
    char* ws = (char*)d_ws;
    u32* wbufs    = (u32*)(ws + 0);
    float* part   = (float*)(ws + 2097152);
    double* Ssum  = (double*)(ws + 2097152 + 32768);
    double* dotv  = (double*)(ws + 2097152 + 32768 + 4096);
    double* sumyv = (double*)(ws + 2097152 + 32768 + 4096 + 2048);
    double* finv  = (double*)(ws + 2097152 + 32768 + 4096 + 4096);
    float* fs     = (float*)(ws + 2097152 + 32768 + 4096 + 4096 + 8);
    float* tsum   = (float*)(ws + 2097152 + 32768 + 4096 + 4096 + 12);

    crf_clear_k<<<256, 256, 0, stream>>>(wbufs, NGROUP * GRPW);
    crf_emit_k<<<32, 256, 0, stream>>>(feats, tags, part);
    crf_trans_k<<<1, 256, 0, stream>>>(trans, tags, start_p, tsum);
    crf_scan_k<<<NGROUP * GPB, TPB, 0, stream>>>(feats, trans, wbufs, Ssum);
    crf_dots_k<<<KCH, 256, 0, stream>>>(wbufs, trans, start_p, stop_p, dotv, sumyv, finv);
    crf_fs_k<<<1, 64, 0, stream>>>(Ssum, dotv, sumyv, finv, fs);
    crf_out_k<<<1, 1024, 0, stream>>>(fs, tsum, part, trans, tags, stop_p, out);
}

// Round 11
// 699.355 us; speedup vs baseline: 18.2911x; 1.3410x over previous
//
#include <hip/hip_runtime.h>
#include <stdint.h>

#define LOG2E_F 1.4426950408889634f
#define LN2_D   0.6931471805599453
#define SEQLEN  16384
#define NTAGS   1024
#define TPB     512
#define NGROUP  32        // 16 fwd + 16 bwd groups
#define GPB     8
#define ROWS    128
#define COFF    13.0f
#define GUARD_MAX 50000

typedef float f32x2 __attribute__((ext_vector_type(2)));
typedef float f32x4 __attribute__((ext_vector_type(4)));
typedef uint32_t u32;
typedef uint64_t u64;

#define REP4(M, B)   M(B) M((B)+1) M((B)+2) M((B)+3)
#define REP16(M, B)  REP4(M, B) REP4(M, (B)+4) REP4(M, (B)+8) REP4(M, (B)+12)
#define REP32(M, B)  REP16(M, B) REP16(M, (B)+16)

#if __has_builtin(__builtin_amdgcn_cvt_pk_fp8_f32) && __has_builtin(__builtin_amdgcn_cvt_pk_f32_fp8)
__device__ __forceinline__ u32 pack4_fp8(float x0, float x1, float x2, float x3) {
    int v = __builtin_amdgcn_cvt_pk_fp8_f32(x0, x1, 0, false);
    v = __builtin_amdgcn_cvt_pk_fp8_f32(x2, x3, v, true);
    return (u32)v;
}
__device__ __forceinline__ float dec8(u32 b) {
    f32x2 r = (f32x2)__builtin_amdgcn_cvt_pk_f32_fp8((int)(b & 0xFFu), false);
    return r.x;
}
#else
__device__ __forceinline__ u32 enc1_fp8(float x) {
    if (x >= 448.f) return 0x7Eu;
    if (x < 0.015625f) { int m = (int)(x * 512.f + 0.5f); return (u32)m; }
    u32 u = __float_as_uint(x);
    u += 0x7FFFFu + ((u >> 20) & 1u);
    int e32 = (int)(u >> 23) - 127;
    if (e32 > 8) return 0x7Eu;
    return (u32)(((e32 + 7) << 3) | ((u >> 20) & 7u));
}
__device__ __forceinline__ u32 pack4_fp8(float x0, float x1, float x2, float x3) {
    return enc1_fp8(x0) | (enc1_fp8(x1) << 8) | (enc1_fp8(x2) << 16) | (enc1_fp8(x3) << 24);
}
__device__ __forceinline__ float dec8(u32 b) {
    b &= 0xFFu;
    u32 e = (b >> 3) & 0xFu, m = b & 7u;
    if (e == 0) return (float)m * 0.001953125f;
    return __uint_as_float(((e + 120u) << 23) | (m << 20));
}
#endif

// ---- prep: clear wire (blocks 0..255) | emit partials (256..287) | trans-sum (288)
__global__ void crf_prep_k(u32* __restrict__ wbufs, int nwords,
                           const float* __restrict__ feats, const int* __restrict__ tags,
                           float* __restrict__ part, const float* __restrict__ trans,
                           const int* __restrict__ start_p, float* __restrict__ tsum) {
    __shared__ int tg[2048];
    __shared__ float red[256];
    const int b = blockIdx.x, tid = threadIdx.x;   // 256 threads
    if (b < 256) {
        for (int i = b * 256 + tid; i < nwords; i += 256 * 256)
            __hip_atomic_store(&wbufs[i], 0xFFFFu, __ATOMIC_RELAXED, __HIP_MEMORY_SCOPE_AGENT);
    } else if (b < 288) {
        const int bb = b - 256, cch = bb >> 2, jb = bb & 3;
        for (int q = tid; q < 2048; q += 256) tg[q] = tags[cch * 2048 + q];
        __syncthreads();
        const int j = jb * 256 + tid;
        float acc = 0.f;
#pragma unroll 8
        for (int k = 0; k < 2048; ++k) acc += feats[(size_t)tg[k] * NTAGS + j];
        part[cch * NTAGS + j] = acc;
    } else {
        const int start = *start_p;
        float acc = 0.f;
        for (int k = 0; k < 64; ++k) {
            const int t = tid * 64 + k;
            const int prev = (t == 0) ? start : tags[t - 1];
            acc += trans[(size_t)tags[t] * NTAGS + prev];
        }
        red[tid] = acc;
        __syncthreads();
        for (int s = 128; s > 0; s >>= 1) { if (tid < s) red[tid] += red[tid + s]; __syncthreads(); }
        if (tid == 0) *tsum = red[0];
    }
}

// K_dir = 16*CPG chunks/direction, LSEG = 1024/CPG steps. Group = 8 blocks x 128 rows.
template <int CPG>
__global__ __launch_bounds__(TPB, 1) void crf_scan_k(
    const float* __restrict__ feats, const float* __restrict__ trans,
    u32* __restrict__ wbufs, double* __restrict__ Ssum)
{
    constexpr int NCT = CPG / 16;          // B col-tiles
    constexpr int TPC = TPB / CPG;         // poller threads per col
    constexpr int LSEG = 1024 / CPG;       // steps
    constexpr int PARW = CPG * 512;        // wire words per parity per group
    extern __shared__ uint2 wBf[];         // [2][32][64*NCT] MFMA B slots
    __shared__ u32 cmaxb[2][CPG];
    __shared__ float fbx[8][16][17];
    __shared__ int okf, deadf;

    const int tid = threadIdx.x;
    const int l = tid & 63, wv = tid >> 6;
    const int g = blockIdx.x >> 3, rank = blockIdx.x & 7;
    const int bwd = g >> 4, gl = g & 15;
    const int row0 = rank * ROWS;
    const int pc = tid / TPC;              // poll col 0..CPG-1
    const int pq = tid % TPC;
    const int pa0 = pq * NCT;              // first covered k-chunk
    const int myc = l & 15, h = l >> 4;
    const int growA = row0 + wv * 16 + myc;
    const int growD = row0 + wv * 16 + h * 4;
    u32* wgrp = wbufs + (size_t)g * (2 * PARW);

    if (tid == 0) { okf = 1; deadf = 0; }
    double Sacc = bwd ? 3.0 : 0.0;         // per-thread; meaningful for tid<CPG

    // ---- init publish (tag 0, parity 0): block's 128 rows x CPG cols ----
    for (int f = tid; f < CPG * 64; f += TPB) {
        const int c = f >> 6, q = f & 63;
        u32 b0, b1;
        if (!bwd) { b0 = b1 = 0x38u; }     // fp8(1.0)
        else {
            const int t = (gl * CPG + c) * LSEG + LSEG - 1;
            const int j0 = row0 + 2 * q;
            const float f0 = feats[(size_t)t * NTAGS + j0]     * LOG2E_F - 3.0f;
            const float f1 = feats[(size_t)t * NTAGS + j0 + 1] * LOG2E_F - 3.0f;
            const u32 pk = pack4_fp8(exp2f(f0), exp2f(f1), 0.f, 0.f);
            b0 = pk & 0xFFu; b1 = (pk >> 8) & 0xFFu;
        }
        __hip_atomic_store(&wgrp[c * 512 + (row0 >> 1) + q], (b1 << 24) | (b0 << 16),
                           __ATOMIC_RELAXED, __HIP_MEMORY_SCOPE_AGENT);
    }

    // ---- stage E as persistent A-fragments (fp8, 64 VGPR) — byte-exact R10 ----
    u64 afr[32];
#define STG(KK) { \
        const int kb = (KK) * 32 + h * 8; \
        float x0,x1,x2,x3,x4,x5,x6,x7; \
        if (!bwd) { \
            const float4 t0 = *(const float4*)&trans[(size_t)growA * NTAGS + kb]; \
            const float4 t1 = *(const float4*)&trans[(size_t)growA * NTAGS + kb + 4]; \
            x0=t0.x; x1=t0.y; x2=t0.z; x3=t0.w; x4=t1.x; x5=t1.y; x6=t1.z; x7=t1.w; \
        } else { \
            x0 = trans[(size_t)(kb+0)*NTAGS + growA]; x1 = trans[(size_t)(kb+1)*NTAGS + growA]; \
            x2 = trans[(size_t)(kb+2)*NTAGS + growA]; x3 = trans[(size_t)(kb+3)*NTAGS + growA]; \
            x4 = trans[(size_t)(kb+4)*NTAGS + growA]; x5 = trans[(size_t)(kb+5)*NTAGS + growA]; \
            x6 = trans[(size_t)(kb+6)*NTAGS + growA]; x7 = trans[(size_t)(kb+7)*NTAGS + growA]; \
        } \
        const u32 lo = pack4_fp8(exp2f(x0*LOG2E_F), exp2f(x1*LOG2E_F), exp2f(x2*LOG2E_F), exp2f(x3*LOG2E_F)); \
        const u32 hi = pack4_fp8(exp2f(x4*LOG2E_F), exp2f(x5*LOG2E_F), exp2f(x6*LOG2E_F), exp2f(x7*LOG2E_F)); \
        afr[KK] = (u64)lo | ((u64)hi << 32); }
    REP32(STG, 0)
#undef STG

    // ---- MFMA layout self-check (exact small-int, asymmetric) — R10 proven ----
    {
        float av0,av1,av2,av3,av4,av5,av6,av7, bv0,bv1,bv2,bv3,bv4,bv5,bv6,bv7;
#define TV(I) { const int k = h*8 + (I); \
        const float a_ = (float)((myc + k) & 3); \
        const float b_ = (float)(((k ^ myc) & 3) + 1); \
        if ((I)==0){av0=a_;bv0=b_;} if ((I)==1){av1=a_;bv1=b_;} \
        if ((I)==2){av2=a_;bv2=b_;} if ((I)==3){av3=a_;bv3=b_;} \
        if ((I)==4){av4=a_;bv4=b_;} if ((I)==5){av5=a_;bv5=b_;} \
        if ((I)==6){av6=a_;bv6=b_;} if ((I)==7){av7=a_;bv7=b_;} }
        TV(0) TV(1) TV(2) TV(3) TV(4) TV(5) TV(6) TV(7)
#undef TV
        const u64 at = (u64)pack4_fp8(av0,av1,av2,av3) | ((u64)pack4_fp8(av4,av5,av6,av7) << 32);
        const u64 bt = (u64)pack4_fp8(bv0,bv1,bv2,bv3) | ((u64)pack4_fp8(bv4,bv5,bv6,bv7) << 32);
        f32x4 dz = {0.f, 0.f, 0.f, 0.f};
        dz = __builtin_amdgcn_mfma_f32_16x16x32_fp8_fp8((long)at, (long)bt, dz, 0, 0, 0);
        bool good = true;
#pragma unroll
        for (int v = 0; v < 4; ++v) {
            const int row = h * 4 + v;
            float e = 0.f;
            for (int k = 0; k < 32; ++k)
                e += (float)(((row + k) & 3) * (((k ^ myc) & 3) + 1));
            good = good && (dz[v] == e);
        }
        if (!good) okf = 0;
    }
    __syncthreads();
    const bool fb = (okf == 0);

    for (int tau = 0; tau < LSEG; ++tau) {
        const int p = tau & 1;
        const u32 tag = (u32)tau;
        const u64 tag2 = ((u64)tag << 32) | tag;

        // feat prefetch (per B col-tile): 4 consecutive D-rows x 1 col
        float4 ffa = make_float4(0.f,0.f,0.f,0.f), ffb = make_float4(0.f,0.f,0.f,0.f);
        {
            int t = -1;
            if (!bwd) t = tau; else if (tau <= LSEG - 2) t = LSEG - 2 - tau;
            if (t >= 0) {
                const int ca = gl * CPG + myc;
                ffa = *(const float4*)&feats[(size_t)(ca * LSEG + t) * NTAGS + growD];
                if (NCT == 2) {
                    const int cb = ca + 16;
                    ffb = *(const float4*)&feats[(size_t)(cb * LSEG + t) * NTAGS + growD];
                }
            }
        }

        // ---- poll NCT k-chunks of col pc (agent-scope, tag-verified) ----
        u32 uu[8 * NCT];
        {
            const u32* pp = wgrp + p * PARW + pc * 512 + pa0 * 16;
            int guard = 0;
            for (;;) {
                u64 v[8 * NCT];
                u64 bad = 0;
#pragma unroll
                for (int q = 0; q < 8 * NCT; ++q) {
                    v[q] = __hip_atomic_load((const u64*)(pp + 2 * q),
                                             __ATOMIC_RELAXED, __HIP_MEMORY_SCOPE_AGENT);
                    bad |= v[q] ^ tag2;
                }
                if (((bad | (bad >> 32)) & 0xFFFFull) == 0ull) {
#pragma unroll
                    for (int q = 0; q < 8 * NCT; ++q)
                        uu[q] = ((u32)v[q] >> 16) | ((u32)(v[q] >> 32) & 0xFFFF0000u);
                    break;
                }
                if (++guard > GUARD_MAX) {
                    deadf = 1;
#pragma unroll
                    for (int q = 0; q < 8 * NCT; ++q) uu[q] = 0;
                    break;
                }
            }
        }
        // B-slot writes: [p][kk][(pc>>4)*64 + h2*16 + (pc&15)]
#pragma unroll
        for (int t2 = 0; t2 < NCT; ++t2)
#pragma unroll
            for (int h2 = 0; h2 < 4; ++h2)
                wBf[((size_t)p * 32 + (pa0 + t2)) * (64 * NCT)
                    + (pc >> 4) * 64 + h2 * 16 + (pc & 15)]
                    = make_uint2(uu[t2 * 8 + 2 * h2], uu[t2 * 8 + 2 * h2 + 1]);
        // col byte-max (fp8 e4m3 positive: integer order = value order)
        {
            u32 bm = 0;
#pragma unroll
            for (int q = 0; q < 8 * NCT; ++q) {
                bm = max(bm, uu[q] & 0xFFu); bm = max(bm, (uu[q] >> 8) & 0xFFu);
                bm = max(bm, (uu[q] >> 16) & 0xFFu); bm = max(bm, uu[q] >> 24);
            }
#pragma unroll
            for (int o = TPC >> 1; o > 0; o >>= 1)
                bm = max(bm, (u32)__shfl_xor((int)bm, o));
            if (pq == 0) cmaxb[p][pc] = bm;
        }
        __syncthreads();                 // B1: slots + cmax ready
        if (deadf) break;

        const float Cme0 = __log2f(dec8(cmaxb[p][myc])) + COFF;
        const float Cme1 = (NCT == 2) ? __log2f(dec8(cmaxb[p][16 + myc])) + COFF : 0.f;
        if (tid < CPG) Sacc += (double)(__log2f(dec8(cmaxb[p][tid])) + COFF);

        // ---- D = E(128x1024) x w(1024xCPG), this wave's 16-row tile ----
        f32x4 accA, accB;
        const uint2* wb = &wBf[(size_t)p * 32 * (64 * NCT)];
        if (!fb) {
            f32x4 a0 = {0.f,0.f,0.f,0.f}, a1 = {0.f,0.f,0.f,0.f};
            f32x4 a2 = {0.f,0.f,0.f,0.f}, a3 = {0.f,0.f,0.f,0.f};
#define MF(KK) { const uint2 f0 = wb[(KK)*(64*NCT) + l]; \
                 const u64 b0 = (u64)f0.x | ((u64)f0.y << 32); \
                 if ((KK) & 1) a1 = __builtin_amdgcn_mfma_f32_16x16x32_fp8_fp8((long)afr[KK], (long)b0, a1, 0,0,0); \
                 else          a0 = __builtin_amdgcn_mfma_f32_16x16x32_fp8_fp8((long)afr[KK], (long)b0, a0, 0,0,0); \
                 if (NCT == 2) { const uint2 f1 = wb[(KK)*(64*NCT) + 64 + l]; \
                   const u64 b1v = (u64)f1.x | ((u64)f1.y << 32); \
                   if ((KK) & 1) a3 = __builtin_amdgcn_mfma_f32_16x16x32_fp8_fp8((long)afr[KK], (long)b1v, a3, 0,0,0); \
                   else          a2 = __builtin_amdgcn_mfma_f32_16x16x32_fp8_fp8((long)afr[KK], (long)b1v, a2, 0,0,0); } }
            REP32(MF, 0)
#undef MF
            accA = a0 + a1; accB = a2 + a3;
        } else {
            // layout-assumption-free VALU fallback (slow, correct)
            for (int bt = 0; bt < NCT; ++bt) {
                float a16[16];
#pragma unroll
                for (int c = 0; c < 16; ++c) a16[c] = 0.f;
                for (int kk = 0; kk < 32; ++kk) {
                    const u64 av = afr[kk];
                    float ea0 = dec8((u32)av), ea1 = dec8((u32)(av>>8)), ea2 = dec8((u32)(av>>16)), ea3 = dec8((u32)(av>>24));
                    float ea4 = dec8((u32)(av>>32)), ea5 = dec8((u32)(av>>40)), ea6 = dec8((u32)(av>>48)), ea7 = dec8((u32)(av>>56));
#pragma unroll
                    for (int c = 0; c < 16; ++c) {
                        const uint2 bfr = wb[kk * (64 * NCT) + bt * 64 + h * 16 + c];
                        const u64 bv = (u64)bfr.x | ((u64)bfr.y << 32);
                        float s = fmaf(ea0, dec8((u32)bv), 0.f);
                        s = fmaf(ea1, dec8((u32)(bv>>8)), s);  s = fmaf(ea2, dec8((u32)(bv>>16)), s);
                        s = fmaf(ea3, dec8((u32)(bv>>24)), s); s = fmaf(ea4, dec8((u32)(bv>>32)), s);
                        s = fmaf(ea5, dec8((u32)(bv>>40)), s); s = fmaf(ea6, dec8((u32)(bv>>48)), s);
                        s = fmaf(ea7, dec8((u32)(bv>>56)), s);
                        a16[c] += s;
                    }
                }
#pragma unroll
                for (int c = 0; c < 16; ++c) {
                    float v2 = a16[c];
                    v2 += __shfl_xor(v2, 16); v2 += __shfl_xor(v2, 32);
                    a16[c] = v2;
                }
                if (h == 0) {
#pragma unroll
                    for (int c = 0; c < 16; ++c) fbx[wv][myc][c] = a16[c];
                }
                __syncthreads();
                f32x4 r;
                r.x = fbx[wv][h*4+0][myc]; r.y = fbx[wv][h*4+1][myc];
                r.z = fbx[wv][h*4+2][myc]; r.w = fbx[wv][h*4+3][myc];
                if (bt == 0) accA = r; else accB = r;
                __syncthreads();
            }
        }

        // ---- publish tag tau+1 (parity p^1) ----
        {
            const u32 ntag = tag + 1u;
            u32* pb = wgrp + (p ^ 1) * PARW;
            {
                u32* pub = pb + myc * 512 + (growD >> 1);
                const float w0 = accA.x * exp2f(fmaf(ffa.x, LOG2E_F, -Cme0));
                const float w1 = accA.y * exp2f(fmaf(ffa.y, LOG2E_F, -Cme0));
                const float w2 = accA.z * exp2f(fmaf(ffa.z, LOG2E_F, -Cme0));
                const float w3 = accA.w * exp2f(fmaf(ffa.w, LOG2E_F, -Cme0));
                const u32 pk = pack4_fp8(w0, w1, w2, w3);
                __hip_atomic_store(&pub[0], ((pk & 0xFFFFu) << 16) | ntag,
                                   __ATOMIC_RELAXED, __HIP_MEMORY_SCOPE_AGENT);
                __hip_atomic_store(&pub[1], (pk & 0xFFFF0000u) | ntag,
                                   __ATOMIC_RELAXED, __HIP_MEMORY_SCOPE_AGENT);
            }
            if (NCT == 2) {
                u32* pub = pb + (16 + myc) * 512 + (growD >> 1);
                const float w0 = accB.x * exp2f(fmaf(ffb.x, LOG2E_F, -Cme1));
                const float w1 = accB.y * exp2f(fmaf(ffb.y, LOG2E_F, -Cme1));
                const float w2 = accB.z * exp2f(fmaf(ffb.z, LOG2E_F, -Cme1));
                const float w3 = accB.w * exp2f(fmaf(ffb.w, LOG2E_F, -Cme1));
                const u32 pk = pack4_fp8(w0, w1, w2, w3);
                __hip_atomic_store(&pub[0], ((pk & 0xFFFFu) << 16) | ntag,
                                   __ATOMIC_RELAXED, __HIP_MEMORY_SCOPE_AGENT);
                __hip_atomic_store(&pub[1], (pk & 0xFFFF0000u) | ntag,
                                   __ATOMIC_RELAXED, __HIP_MEMORY_SCOPE_AGENT);
            }
        }
    }

    if (rank == 0 && tid < CPG)
        Ssum[bwd * (16 * CPG) + gl * CPG + tid] = Sacc;
}

// sumy[c]=1'y_c ; dot[c]=z_c.y_{c-1} (c>0), dot[0]=z_0[start]; fin=y_{K-1}.exp(T[stop,:])
__global__ void crf_dots_k(const u32* __restrict__ wbufs, const float* __restrict__ trans,
                           const int* __restrict__ start_p, const int* __restrict__ stop_p,
                           double* __restrict__ dotv, double* __restrict__ sumyv,
                           double* __restrict__ finv, int CPG, int K)
{
    const int c = blockIdx.x;        // 0..K-1
    const int tid = threadIdx.x;     // 256
    __shared__ double red[256];
    const int GRPW = 2 * CPG * 512;
    const u32* y = wbufs + (size_t)(c / CPG) * GRPW + (c % CPG) * 512;
    const u32* z = wbufs + (size_t)(16 + c / CPG) * GRPW + (c % CPG) * 512;
    const int cm = c - 1;
    const u32* ym1 = (c > 0) ? (wbufs + (size_t)(cm / CPG) * GRPW + (cm % CPG) * 512) : nullptr;
    const int stop = *stop_p;

    double sy = 0, dt = 0, fn = 0;
    for (int jp = tid; jp < 512; jp += 256) {
        const u32 wy = y[jp];
        const double y0 = (double)dec8((wy >> 16) & 0xFFu), y1 = (double)dec8(wy >> 24);
        sy += y0 + y1;
        if (c > 0) {
            const u32 wz = z[jp], wm = ym1[jp];
            dt += (double)dec8((wz >> 16) & 0xFFu) * (double)dec8((wm >> 16) & 0xFFu)
                + (double)dec8(wz >> 24) * (double)dec8(wm >> 24);
        }
        if (c == K - 1)
            fn += y0 * (double)__expf(trans[(size_t)stop * NTAGS + 2*jp])
                + y1 * (double)__expf(trans[(size_t)stop * NTAGS + 2*jp + 1]);
    }
    red[tid] = sy; __syncthreads();
    for (int s = 128; s > 0; s >>= 1) { if (tid < s) red[tid] += red[tid + s]; __syncthreads(); }
    if (tid == 0) sumyv[c] = red[0];
    __syncthreads();
    red[tid] = dt; __syncthreads();
    for (int s = 128; s > 0; s >>= 1) { if (tid < s) red[tid] += red[tid + s]; __syncthreads(); }
    if (tid == 0 && c > 0) dotv[c] = red[0];
    __syncthreads();
    red[tid] = fn; __syncthreads();
    for (int s = 128; s > 0; s >>= 1) { if (tid < s) red[tid] += red[tid + s]; __syncthreads(); }
    if (tid == 0 && c == K - 1) finv[0] = red[0];
    if (tid == 0 && c == 0) {
        const int st = *start_p;
        const u32 wz = z[st >> 1];
        dotv[0] = (double)dec8((st & 1) ? (wz >> 24) : ((wz >> 16) & 0xFFu));
    }
}

// finish: parallel chunk-composition (fs) + output vector
__global__ void crf_finish_k(const double* __restrict__ Ssum, const double* __restrict__ dotv,
                             const double* __restrict__ sumyv, const double* __restrict__ finv,
                             const float* __restrict__ tsum, const float* __restrict__ part,
                             const float* __restrict__ trans, const int* __restrict__ tags,
                             const int* __restrict__ stop_p, float* __restrict__ out, int K)
{
    __shared__ double red[1024];
    __shared__ float fsv;
    const int tid = threadIdx.x;   // 1024
    const double* Ssf = Ssum;
    const double* Ssb = Ssum + K;
    double t = 0.0;
    if (tid == 0)
        t = log2(dotv[0]) + Ssb[0] - log2(sumyv[0]) - Ssf[0]
          + log2(finv[0]) + Ssf[K - 1];
    else if (tid < K)
        t = log2(dotv[tid]) + Ssb[tid] + Ssf[tid - 1] - log2(sumyv[tid]) - Ssf[tid];
    red[tid] = t; __syncthreads();
    for (int s = 512; s > 0; s >>= 1) { if (tid < s) red[tid] += red[tid + s]; __syncthreads(); }
    if (tid == 0) fsv = (float)(LN2_D * red[0]);
    __syncthreads();
    float e = 0.f;
    for (int cc = 0; cc < 8; ++cc) e += part[cc * NTAGS + tid];
    const int stop = *stop_p;
    const int last = tags[SEQLEN - 1];
    out[tid] = fsv - (tsum[0] + e + trans[(size_t)stop * NTAGS + last]);
}

extern "C" void kernel_launch(void* const* d_in, const int* in_sizes, int n_in,
                              void* d_out, int out_size, void* d_ws, size_t ws_size,
                              hipStream_t stream) {
    const float* feats = (const float*)d_in[0];
    const float* trans = (const float*)d_in[1];
    const int* tags    = (const int*)d_in[2];
    const int* start_p = (const int*)d_in[3];
    const int* stop_p  = (const int*)d_in[4];
    float* out = (float*)d_out;

    // adaptive: CPG=32 (L=32 steps, wire 4.19MB) if ws allows, else proven CPG=16
    const int CPG = (ws_size >= 4300800ull) ? 32 : 16;
    const int K = 16 * CPG;
    const size_t wireB = (size_t)CPG * 131072ull;   // 32 grp x 2 par x CPG x 512 x 4B

    char* ws = (char*)d_ws;
    u32* wbufs    = (u32*)(ws + 0);
    float* part   = (float*)(ws + wireB);
    double* Ssum  = (double*)(ws + wireB + 32768);
    double* dotv  = (double*)(ws + wireB + 32768 + 8192);
    double* sumyv = (double*)(ws + wireB + 32768 + 16384);
    double* finv  = (double*)(ws + wireB + 32768 + 24576);
    float* fs_pad = (float*)(ws + wireB + 32768 + 24584);
    float* tsum   = fs_pad;   // 4B scalar
    const int nwords = 32 * 2 * CPG * 512;

    crf_prep_k<<<289, 256, 0, stream>>>(wbufs, nwords, feats, tags, part, trans, start_p, tsum);

    if (CPG == 32) {
        (void)hipFuncSetAttribute((const void*)crf_scan_k<32>,
                                  hipFuncAttributeMaxDynamicSharedMemorySize, 65536);
        crf_scan_k<32><<<NGROUP * GPB, TPB, 65536, stream>>>(feats, trans, wbufs, Ssum);
    } else {
        (void)hipFuncSetAttribute((const void*)crf_scan_k<16>,
                                  hipFuncAttributeMaxDynamicSharedMemorySize, 32768);
        crf_scan_k<16><<<NGROUP * GPB, TPB, 32768, stream>>>(feats, trans, wbufs, Ssum);
    }

    crf_dots_k<<<K, 256, 0, stream>>>(wbufs, trans, start_p, stop_p, dotv, sumyv, finv, CPG, K);
    crf_finish_k<<<1, 1024, 0, stream>>>(Ssum, dotv, sumyv, finv, tsum, part, trans, tags,
                                         stop_p, out, K);
}

// Round 12
// 452.071 us; speedup vs baseline: 28.2964x; 1.5470x over previous
//
#include <hip/hip_runtime.h>
#include <stdint.h>

#define LOG2E_F 1.4426950408889634f
#define LN2_D   0.6931471805599453
#define SEQLEN  16384
#define NTAGS   1024
#define TPB     512
#define NGROUP  32        // 16 fwd + 16 bwd groups
#define GPB     8
#define ROWS    128
#define CPG     16        // chunk-columns per group = MFMA N
#define LSEG    64        // steps per chunk
#define KCH     256       // chunks per direction
#define COFF    13.0f
#define GUARD_MAX 100000
#define PARW    (CPG * 512)

typedef float f32x2 __attribute__((ext_vector_type(2)));
typedef float f32x4 __attribute__((ext_vector_type(4)));
typedef uint32_t u32;
typedef uint64_t u64;

#define REP4(M, B)   M(B) M((B)+1) M((B)+2) M((B)+3)
#define REP16(M, B)  REP4(M, B) REP4(M, (B)+4) REP4(M, (B)+8) REP4(M, (B)+12)
#define REP32(M, B)  REP16(M, B) REP16(M, (B)+16)

#if __has_builtin(__builtin_amdgcn_cvt_pk_fp8_f32) && __has_builtin(__builtin_amdgcn_cvt_pk_f32_fp8)
__device__ __forceinline__ u32 pack4_fp8(float x0, float x1, float x2, float x3) {
    int v = __builtin_amdgcn_cvt_pk_fp8_f32(x0, x1, 0, false);
    v = __builtin_amdgcn_cvt_pk_fp8_f32(x2, x3, v, true);
    return (u32)v;
}
__device__ __forceinline__ float dec8(u32 b) {
    f32x2 r = (f32x2)__builtin_amdgcn_cvt_pk_f32_fp8((int)(b & 0xFFu), false);
    return r.x;
}
#else
__device__ __forceinline__ u32 enc1_fp8(float x) {
    if (x >= 448.f) return 0x7Eu;
    if (x < 0.015625f) { int m = (int)(x * 512.f + 0.5f); return (u32)m; }
    u32 u = __float_as_uint(x);
    u += 0x7FFFFu + ((u >> 20) & 1u);
    int e32 = (int)(u >> 23) - 127;
    if (e32 > 8) return 0x7Eu;
    return (u32)(((e32 + 7) << 3) | ((u >> 20) & 7u));
}
__device__ __forceinline__ u32 pack4_fp8(float x0, float x1, float x2, float x3) {
    return enc1_fp8(x0) | (enc1_fp8(x1) << 8) | (enc1_fp8(x2) << 16) | (enc1_fp8(x3) << 24);
}
__device__ __forceinline__ float dec8(u32 b) {
    b &= 0xFFu;
    u32 e = (b >> 3) & 0xFu, m = b & 7u;
    if (e == 0) return (float)m * 0.001953125f;
    return __uint_as_float(((e + 120u) << 23) | (m << 20));
}
#endif

// prep: clear wire+flags (blocks 0..255) | emit partials (256..287) | trans-sum (288)
__global__ void crf_prep_k(u32* __restrict__ wbufs, int nwords, u32* __restrict__ flags,
                           const float* __restrict__ feats, const int* __restrict__ tags,
                           float* __restrict__ part, const float* __restrict__ trans,
                           const int* __restrict__ start_p, float* __restrict__ tsum) {
    __shared__ int tg[2048];
    __shared__ float red[256];
    const int b = blockIdx.x, tid = threadIdx.x;   // 256 threads
    if (b < 256) {
        for (int i = b * 256 + tid; i < nwords; i += 256 * 256)
            __hip_atomic_store(&wbufs[i], 0xFFFFu, __ATOMIC_RELAXED, __HIP_MEMORY_SCOPE_AGENT);
        if (b == 0)
            for (int i = tid; i < NGROUP * 16; i += 256)
                __hip_atomic_store(&flags[i], 0xFFFFu, __ATOMIC_RELAXED, __HIP_MEMORY_SCOPE_AGENT);
    } else if (b < 288) {
        const int bb = b - 256, cch = bb >> 2, jb = bb & 3;
        for (int q = tid; q < 2048; q += 256) tg[q] = tags[cch * 2048 + q];
        __syncthreads();
        const int j = jb * 256 + tid;
        float acc = 0.f;
#pragma unroll 8
        for (int k = 0; k < 2048; ++k) acc += feats[(size_t)tg[k] * NTAGS + j];
        part[cch * NTAGS + j] = acc;
    } else {
        const int start = *start_p;
        float acc = 0.f;
        for (int k = 0; k < 64; ++k) {
            const int t = tid * 64 + k;
            const int prev = (t == 0) ? start : tags[t - 1];
            acc += trans[(size_t)tags[t] * NTAGS + prev];
        }
        red[tid] = acc;
        __syncthreads();
        for (int s = 128; s > 0; s >>= 1) { if (tid < s) red[tid] += red[tid + s]; __syncthreads(); }
        if (tid == 0) *tsum = red[0];
    }
}

__global__ __launch_bounds__(TPB, 1) void crf_scan_k(
    const float* __restrict__ feats, const float* __restrict__ trans,
    u32* __restrict__ wbufs, u32* __restrict__ flags, double* __restrict__ Ssum)
{
    __shared__ uint2 wBf[2][32][64];     // MFMA B slots, double-buffered
    __shared__ u32 cmaxb[2][CPG];
    __shared__ float fbx[8][16][17];     // fallback transpose buffer
    __shared__ int okf, deadf;

    const int tid = threadIdx.x;
    const int l = tid & 63, wv = tid >> 6;
    // swizzle: ranks of a group land 32 apart in dispatch -> same XCD (perf only)
    const int g = blockIdx.x & 31, rank = blockIdx.x >> 5;
    const int bwd = g >> 4, gl = g & 15;
    const int row0 = rank * ROWS;
    const int pc = tid >> 5, pq = tid & 31;    // poller: col, k-chunk
    const int myc = l & 15, h = l >> 4;
    const int growA = row0 + wv * 16 + myc;
    const int growD = row0 + wv * 16 + h * 4;
    u32* wgrp = wbufs + (size_t)g * (2 * PARW);
    u32* fgrp = flags + g * 16;                // [parity][rank]

    if (tid == 0) { okf = 1; deadf = 0; }
    double Sacc = bwd ? 3.0 : 0.0;             // meaningful for tid < CPG

    // ---- init publish (tag 0, parity 0) ----
    for (int f = tid; f < CPG * 64; f += TPB) {
        const int c = f >> 6, q = f & 63;
        u32 b0, b1;
        if (!bwd) { b0 = b1 = 0x38u; }         // fp8(1.0)
        else {
            const int t = (gl * CPG + c) * LSEG + LSEG - 1;
            const int j0 = row0 + 2 * q;
            const float f0 = feats[(size_t)t * NTAGS + j0]     * LOG2E_F - 3.0f;
            const float f1 = feats[(size_t)t * NTAGS + j0 + 1] * LOG2E_F - 3.0f;
            const u32 pk = pack4_fp8(exp2f(f0), exp2f(f1), 0.f, 0.f);
            b0 = pk & 0xFFu; b1 = (pk >> 8) & 0xFFu;
        }
        __hip_atomic_store(&wgrp[c * 512 + (row0 >> 1) + q], (b1 << 24) | (b0 << 16),
                           __ATOMIC_RELAXED, __HIP_MEMORY_SCOPE_AGENT);
    }
    asm volatile("s_waitcnt vmcnt(0)" ::: "memory");   // init data drained
    __syncthreads();
    if (tid == 0)
        __hip_atomic_store(&fgrp[0 * 8 + rank], 0u, __ATOMIC_RELAXED, __HIP_MEMORY_SCOPE_AGENT);

    // ---- stage E as persistent A-fragments (fp8, 64 VGPR) — R10-proven ----
    u64 afr[32];
#define STG(KK) { \
        const int kb = (KK) * 32 + h * 8; \
        float x0,x1,x2,x3,x4,x5,x6,x7; \
        if (!bwd) { \
            const float4 t0 = *(const float4*)&trans[(size_t)growA * NTAGS + kb]; \
            const float4 t1 = *(const float4*)&trans[(size_t)growA * NTAGS + kb + 4]; \
            x0=t0.x; x1=t0.y; x2=t0.z; x3=t0.w; x4=t1.x; x5=t1.y; x6=t1.z; x7=t1.w; \
        } else { \
            x0 = trans[(size_t)(kb+0)*NTAGS + growA]; x1 = trans[(size_t)(kb+1)*NTAGS + growA]; \
            x2 = trans[(size_t)(kb+2)*NTAGS + growA]; x3 = trans[(size_t)(kb+3)*NTAGS + growA]; \
            x4 = trans[(size_t)(kb+4)*NTAGS + growA]; x5 = trans[(size_t)(kb+5)*NTAGS + growA]; \
            x6 = trans[(size_t)(kb+6)*NTAGS + growA]; x7 = trans[(size_t)(kb+7)*NTAGS + growA]; \
        } \
        const u32 lo = pack4_fp8(exp2f(x0*LOG2E_F), exp2f(x1*LOG2E_F), exp2f(x2*LOG2E_F), exp2f(x3*LOG2E_F)); \
        const u32 hi = pack4_fp8(exp2f(x4*LOG2E_F), exp2f(x5*LOG2E_F), exp2f(x6*LOG2E_F), exp2f(x7*LOG2E_F)); \
        afr[KK] = (u64)lo | ((u64)hi << 32); }
    REP32(STG, 0)
#undef STG

    // ---- MFMA layout self-check (exact small-int, asymmetric) — R10-proven ----
    {
        float av0,av1,av2,av3,av4,av5,av6,av7, bv0,bv1,bv2,bv3,bv4,bv5,bv6,bv7;
#define TV(I) { const int k = h*8 + (I); \
        const float a_ = (float)((myc + k) & 3); \
        const float b_ = (float)(((k ^ myc) & 3) + 1); \
        if ((I)==0){av0=a_;bv0=b_;} if ((I)==1){av1=a_;bv1=b_;} \
        if ((I)==2){av2=a_;bv2=b_;} if ((I)==3){av3=a_;bv3=b_;} \
        if ((I)==4){av4=a_;bv4=b_;} if ((I)==5){av5=a_;bv5=b_;} \
        if ((I)==6){av6=a_;bv6=b_;} if ((I)==7){av7=a_;bv7=b_;} }
        TV(0) TV(1) TV(2) TV(3) TV(4) TV(5) TV(6) TV(7)
#undef TV
        const u64 at = (u64)pack4_fp8(av0,av1,av2,av3) | ((u64)pack4_fp8(av4,av5,av6,av7) << 32);
        const u64 bt = (u64)pack4_fp8(bv0,bv1,bv2,bv3) | ((u64)pack4_fp8(bv4,bv5,bv6,bv7) << 32);
        f32x4 dz = {0.f, 0.f, 0.f, 0.f};
        dz = __builtin_amdgcn_mfma_f32_16x16x32_fp8_fp8((long)at, (long)bt, dz, 0, 0, 0);
        bool good = true;
#pragma unroll
        for (int v = 0; v < 4; ++v) {
            const int row = h * 4 + v;
            float e = 0.f;
            for (int k = 0; k < 32; ++k)
                e += (float)(((row + k) & 3) * (((k ^ myc) & 3) + 1));
            good = good && (dz[v] == e);
        }
        if (!good) okf = 0;
    }
    __syncthreads();
    const bool fb = (okf == 0);

    for (int tau = 0; tau < LSEG; ++tau) {
        const int p = tau & 1;
        const u32 tag = (u32)tau;
        const u64 tag2 = ((u64)tag << 32) | tag;

        // feat prefetch (issued before the flag wait)
        float4 ff4 = make_float4(0.f, 0.f, 0.f, 0.f);
        {
            int t = -1;
            if (!bwd) t = tau; else if (tau <= LSEG - 2) t = LSEG - 2 - tau;
            if (t >= 0) {
                const int ca = gl * CPG + myc;
                ff4 = *(const float4*)&feats[(size_t)(ca * LSEG + t) * NTAGS + growD];
            }
        }

        // ---- 1. flag discovery: wave 0 only (8 words per group) ----
        if (wv == 0) {
            int guard = 0;
            u32 fv = tag;
            for (;;) {
                if (l < GPB)
                    fv = __hip_atomic_load(&fgrp[p * 8 + l],
                                           __ATOMIC_RELAXED, __HIP_MEMORY_SCOPE_AGENT);
                if (__all(fv == tag)) break;
                if (++guard > GUARD_MAX) { deadf = 1; break; }
            }
        }
        __syncthreads();               // flags seen; deadf visible
        if (deadf) break;

        // ---- 2. single-shot bulk read + tag verify (retry = proven fallback) ----
        u32 uu0,uu1,uu2,uu3,uu4,uu5,uu6,uu7;
        {
            const u32* pp = wgrp + p * PARW + pc * 512 + pq * 16;
            int guard = 0;
            for (;;) {
                u64 v0,v1,v2,v3,v4,v5,v6,v7;
                v0 = __hip_atomic_load((const u64*)(pp+ 0), __ATOMIC_RELAXED, __HIP_MEMORY_SCOPE_AGENT);
                v1 = __hip_atomic_load((const u64*)(pp+ 2), __ATOMIC_RELAXED, __HIP_MEMORY_SCOPE_AGENT);
                v2 = __hip_atomic_load((const u64*)(pp+ 4), __ATOMIC_RELAXED, __HIP_MEMORY_SCOPE_AGENT);
                v3 = __hip_atomic_load((const u64*)(pp+ 6), __ATOMIC_RELAXED, __HIP_MEMORY_SCOPE_AGENT);
                v4 = __hip_atomic_load((const u64*)(pp+ 8), __ATOMIC_RELAXED, __HIP_MEMORY_SCOPE_AGENT);
                v5 = __hip_atomic_load((const u64*)(pp+10), __ATOMIC_RELAXED, __HIP_MEMORY_SCOPE_AGENT);
                v6 = __hip_atomic_load((const u64*)(pp+12), __ATOMIC_RELAXED, __HIP_MEMORY_SCOPE_AGENT);
                v7 = __hip_atomic_load((const u64*)(pp+14), __ATOMIC_RELAXED, __HIP_MEMORY_SCOPE_AGENT);
                u64 bad = (v0^tag2)|(v1^tag2)|(v2^tag2)|(v3^tag2)|(v4^tag2)|(v5^tag2)|(v6^tag2)|(v7^tag2);
                if (((bad | (bad >> 32)) & 0xFFFFull) == 0ull) {
                    uu0 = ((u32)v0 >> 16) | ((u32)(v0>>32) & 0xFFFF0000u);
                    uu1 = ((u32)v1 >> 16) | ((u32)(v1>>32) & 0xFFFF0000u);
                    uu2 = ((u32)v2 >> 16) | ((u32)(v2>>32) & 0xFFFF0000u);
                    uu3 = ((u32)v3 >> 16) | ((u32)(v3>>32) & 0xFFFF0000u);
                    uu4 = ((u32)v4 >> 16) | ((u32)(v4>>32) & 0xFFFF0000u);
                    uu5 = ((u32)v5 >> 16) | ((u32)(v5>>32) & 0xFFFF0000u);
                    uu6 = ((u32)v6 >> 16) | ((u32)(v6>>32) & 0xFFFF0000u);
                    uu7 = ((u32)v7 >> 16) | ((u32)(v7>>32) & 0xFFFF0000u);
                    break;
                }
                if (++guard > GUARD_MAX) {
                    deadf = 1; uu0=uu1=uu2=uu3=uu4=uu5=uu6=uu7=0; break;
                }
            }
        }
        // B-slot writes + col byte-max
        wBf[p][pq][ 0 + pc] = make_uint2(uu0, uu1);
        wBf[p][pq][16 + pc] = make_uint2(uu2, uu3);
        wBf[p][pq][32 + pc] = make_uint2(uu4, uu5);
        wBf[p][pq][48 + pc] = make_uint2(uu6, uu7);
        {
            u32 bm = 0;
#define BM(U) { bm = max(bm, (U) & 0xFFu); bm = max(bm, ((U)>>8) & 0xFFu); \
                bm = max(bm, ((U)>>16) & 0xFFu); bm = max(bm, (U)>>24); }
            BM(uu0) BM(uu1) BM(uu2) BM(uu3) BM(uu4) BM(uu5) BM(uu6) BM(uu7)
#undef BM
#pragma unroll
            for (int o = 16; o > 0; o >>= 1) bm = max(bm, (u32)__shfl_xor((int)bm, o));
            if (pq == 0) cmaxb[p][pc] = bm;
        }
        __syncthreads();                 // B1: slots + cmax ready
        if (deadf) break;

        const float Cme = __log2f(dec8(cmaxb[p][myc])) + COFF;
        if (tid < CPG) Sacc += (double)(__log2f(dec8(cmaxb[p][tid])) + COFF);

        // ---- 3. D = E(128x1024) x w(1024x16) ----
        f32x4 acc;
        const uint2* wb = &wBf[p][0][0];
        if (!fb) {
            f32x4 a0 = {0.f,0.f,0.f,0.f}, a1 = {0.f,0.f,0.f,0.f};
#define MF(KK) { const uint2 bfr = wb[(KK)*64 + l]; \
                 const u64 bb = (u64)bfr.x | ((u64)bfr.y << 32); \
                 if ((KK) & 1) a1 = __builtin_amdgcn_mfma_f32_16x16x32_fp8_fp8((long)afr[KK], (long)bb, a1, 0,0,0); \
                 else          a0 = __builtin_amdgcn_mfma_f32_16x16x32_fp8_fp8((long)afr[KK], (long)bb, a0, 0,0,0); }
            REP32(MF, 0)
#undef MF
            acc = a0 + a1;
        } else {
            float a16[16];
#pragma unroll
            for (int c = 0; c < 16; ++c) a16[c] = 0.f;
            for (int kk = 0; kk < 32; ++kk) {
                const u64 av = afr[kk];
                float ea0 = dec8((u32)av), ea1 = dec8((u32)(av>>8)), ea2 = dec8((u32)(av>>16)), ea3 = dec8((u32)(av>>24));
                float ea4 = dec8((u32)(av>>32)), ea5 = dec8((u32)(av>>40)), ea6 = dec8((u32)(av>>48)), ea7 = dec8((u32)(av>>56));
#pragma unroll
                for (int c = 0; c < 16; ++c) {
                    const uint2 bfr = wb[kk*64 + h*16 + c];
                    const u64 bv = (u64)bfr.x | ((u64)bfr.y << 32);
                    float s = fmaf(ea0, dec8((u32)bv), 0.f);
                    s = fmaf(ea1, dec8((u32)(bv>>8)), s);  s = fmaf(ea2, dec8((u32)(bv>>16)), s);
                    s = fmaf(ea3, dec8((u32)(bv>>24)), s); s = fmaf(ea4, dec8((u32)(bv>>32)), s);
                    s = fmaf(ea5, dec8((u32)(bv>>40)), s); s = fmaf(ea6, dec8((u32)(bv>>48)), s);
                    s = fmaf(ea7, dec8((u32)(bv>>56)), s);
                    a16[c] += s;
                }
            }
#pragma unroll
            for (int c = 0; c < 16; ++c) {
                float v2 = a16[c];
                v2 += __shfl_xor(v2, 16); v2 += __shfl_xor(v2, 32);
                a16[c] = v2;
            }
            if (h == 0) {
#pragma unroll
                for (int c = 0; c < 16; ++c) fbx[wv][myc][c] = a16[c];
            }
            __syncthreads();
            acc.x = fbx[wv][h*4+0][myc]; acc.y = fbx[wv][h*4+1][myc];
            acc.z = fbx[wv][h*4+2][myc]; acc.w = fbx[wv][h*4+3][myc];
        }

        // ---- 4. publish tag tau+1 -> parity p^1; drain; barrier; flag ----
        {
            const u32 ntag = tag + 1u;
            u32* pub = wgrp + (p ^ 1) * PARW + myc * 512 + (growD >> 1);
            const float w0 = acc.x * exp2f(fmaf(ff4.x, LOG2E_F, -Cme));
            const float w1 = acc.y * exp2f(fmaf(ff4.y, LOG2E_F, -Cme));
            const float w2 = acc.z * exp2f(fmaf(ff4.z, LOG2E_F, -Cme));
            const float w3 = acc.w * exp2f(fmaf(ff4.w, LOG2E_F, -Cme));
            const u32 pk = pack4_fp8(w0, w1, w2, w3);
            __hip_atomic_store(&pub[0], ((pk & 0xFFFFu) << 16) | ntag,
                               __ATOMIC_RELAXED, __HIP_MEMORY_SCOPE_AGENT);
            __hip_atomic_store(&pub[1], (pk & 0xFFFF0000u) | ntag,
                               __ATOMIC_RELAXED, __HIP_MEMORY_SCOPE_AGENT);
        }
        asm volatile("s_waitcnt vmcnt(0)" ::: "memory");   // data drained (per wave)
        __syncthreads();                                    // all waves drained
        if (tid == 0)
            __hip_atomic_store(&fgrp[(p ^ 1) * 8 + rank], tag + 1u,
                               __ATOMIC_RELAXED, __HIP_MEMORY_SCOPE_AGENT);
    }

    if (rank == 0 && tid < CPG)
        Ssum[bwd * KCH + gl * CPG + tid] = Sacc;
}

// sumy[c]=1'y_c ; dot[c]=z_c.y_{c-1} (c>0), dot[0]=z_0[start]; fin=y_{K-1}.exp(T[stop,:])
__global__ void crf_dots_k(const u32* __restrict__ wbufs, const float* __restrict__ trans,
                           const int* __restrict__ start_p, const int* __restrict__ stop_p,
                           double* __restrict__ dotv, double* __restrict__ sumyv,
                           double* __restrict__ finv)
{
    const int c = blockIdx.x;        // 0..255
    const int tid = threadIdx.x;     // 256
    __shared__ double red[256];
    const int GRPW = 2 * PARW;
    const u32* y = wbufs + (size_t)(c / CPG) * GRPW + (c % CPG) * 512;
    const u32* z = wbufs + (size_t)(16 + c / CPG) * GRPW + (c % CPG) * 512;
    const int cm = c - 1;
    const u32* ym1 = (c > 0) ? (wbufs + (size_t)(cm / CPG) * GRPW + (cm % CPG) * 512) : nullptr;
    const int stop = *stop_p;

    double sy = 0, dt = 0, fn = 0;
    for (int jp = tid; jp < 512; jp += 256) {
        const u32 wy = y[jp];
        const double y0 = (double)dec8((wy >> 16) & 0xFFu), y1 = (double)dec8(wy >> 24);
        sy += y0 + y1;
        if (c > 0) {
            const u32 wz = z[jp], wm = ym1[jp];
            dt += (double)dec8((wz >> 16) & 0xFFu) * (double)dec8((wm >> 16) & 0xFFu)
                + (double)dec8(wz >> 24) * (double)dec8(wm >> 24);
        }
        if (c == KCH - 1)
            fn += y0 * (double)__expf(trans[(size_t)stop * NTAGS + 2*jp])
                + y1 * (double)__expf(trans[(size_t)stop * NTAGS + 2*jp + 1]);
    }
    red[tid] = sy; __syncthreads();
    for (int s = 128; s > 0; s >>= 1) { if (tid < s) red[tid] += red[tid + s]; __syncthreads(); }
    if (tid == 0) sumyv[c] = red[0];
    __syncthreads();
    red[tid] = dt; __syncthreads();
    for (int s = 128; s > 0; s >>= 1) { if (tid < s) red[tid] += red[tid + s]; __syncthreads(); }
    if (tid == 0 && c > 0) dotv[c] = red[0];
    __syncthreads();
    red[tid] = fn; __syncthreads();
    for (int s = 128; s > 0; s >>= 1) { if (tid < s) red[tid] += red[tid + s]; __syncthreads(); }
    if (tid == 0 && c == KCH - 1) finv[0] = red[0];
    if (tid == 0 && c == 0) {
        const int st = *start_p;
        const u32 wz = z[st >> 1];
        dotv[0] = (double)dec8((st & 1) ? (wz >> 24) : ((wz >> 16) & 0xFFu));
    }
}

// finish: parallel chunk-composition (fs) + output vector
__global__ void crf_finish_k(const double* __restrict__ Ssum, const double* __restrict__ dotv,
                             const double* __restrict__ sumyv, const double* __restrict__ finv,
                             const float* __restrict__ tsum, const float* __restrict__ part,
                             const float* __restrict__ trans, const int* __restrict__ tags,
                             const int* __restrict__ stop_p, float* __restrict__ out)
{
    __shared__ double red[1024];
    __shared__ float fsv;
    const int tid = threadIdx.x;   // 1024
    const double* Ssf = Ssum;
    const double* Ssb = Ssum + KCH;
    double t = 0.0;
    if (tid == 0)
        t = log2(dotv[0]) + Ssb[0] - log2(sumyv[0]) - Ssf[0]
          + log2(finv[0]) + Ssf[KCH - 1];
    else if (tid < KCH)
        t = log2(dotv[tid]) + Ssb[tid] + Ssf[tid - 1] - log2(sumyv[tid]) - Ssf[tid];
    red[tid] = t; __syncthreads();
    for (int s = 512; s > 0; s >>= 1) { if (tid < s) red[tid] += red[tid + s]; __syncthreads(); }
    if (tid == 0) fsv = (float)(LN2_D * red[0]);
    __syncthreads();
    float e = 0.f;
    for (int cc = 0; cc < 8; ++cc) e += part[cc * NTAGS + tid];
    const int stop = *stop_p;
    const int last = tags[SEQLEN - 1];
    out[tid] = fsv - (tsum[0] + e + trans[(size_t)stop * NTAGS + last]);
}

extern "C" void kernel_launch(void* const* d_in, const int* in_sizes, int n_in,
                              void* d_out, int out_size, void* d_ws, size_t ws_size,
                              hipStream_t stream) {
    const float* feats = (const float*)d_in[0];
    const float* trans = (const float*)d_in[1];
    const int* tags    = (const int*)d_in[2];
    const int* start_p = (const int*)d_in[3];
    const int* stop_p  = (const int*)d_in[4];
    float* out = (float*)d_out;

    // ws: wire 2MB | part 32KB | Ssum 4KB | dotv/sumyv 2KB | finv/tsum | flags 2KB
    char* ws = (char*)d_ws;
    u32* wbufs    = (u32*)(ws + 0);
    float* part   = (float*)(ws + 2097152);
    double* Ssum  = (double*)(ws + 2129920);
    double* dotv  = (double*)(ws + 2134016);
    double* sumyv = (double*)(ws + 2136064);
    double* finv  = (double*)(ws + 2138112);
    float* tsum   = (float*)(ws + 2138120);
    u32* flags    = (u32*)(ws + 2138624);
    const int nwords = NGROUP * 2 * PARW;

    crf_prep_k<<<289, 256, 0, stream>>>(wbufs, nwords, flags, feats, tags, part,
                                        trans, start_p, tsum);
    crf_scan_k<<<NGROUP * GPB, TPB, 0, stream>>>(feats, trans, wbufs, flags, Ssum);
    crf_dots_k<<<KCH, 256, 0, stream>>>(wbufs, trans, start_p, stop_p, dotv, sumyv, finv);
    crf_finish_k<<<1, 1024, 0, stream>>>(Ssum, dotv, sumyv, finv, tsum, part, trans, tags,
                                         stop_p, out);
}

// Round 13
// 323.891 us; speedup vs baseline: 39.4947x; 1.3958x over previous
//
#include <hip/hip_runtime.h>
#include <stdint.h>

#define LOG2E_F 1.4426950408889634f
#define LN2_D   0.6931471805599453
#define SEQLEN  16384
#define NTAGS   1024
#define TPB     512
#define NGROUP  32        // 16 fwd + 16 bwd groups
#define GPB     8
#define ROWS    128
#define CPG     32        // chunk-columns per group (2 MFMA B-tiles)
#define LSEG    32        // steps per chunk
#define KCH     512       // chunks per direction
#define COFF    13.0f
#define GUARD_MAX 100000
#define PARW    (CPG * 256)   // tagless wire: 256 u32 words (1024 fp8 rows) per col

typedef float f32x2 __attribute__((ext_vector_type(2)));
typedef float f32x4 __attribute__((ext_vector_type(4)));
typedef uint32_t u32;
typedef uint64_t u64;

#define REP4(M, B)   M(B) M((B)+1) M((B)+2) M((B)+3)
#define REP16(M, B)  REP4(M, B) REP4(M, (B)+4) REP4(M, (B)+8) REP4(M, (B)+12)
#define REP32(M, B)  REP16(M, B) REP16(M, (B)+16)

#if __has_builtin(__builtin_amdgcn_cvt_pk_fp8_f32) && __has_builtin(__builtin_amdgcn_cvt_pk_f32_fp8)
__device__ __forceinline__ u32 pack4_fp8(float x0, float x1, float x2, float x3) {
    int v = __builtin_amdgcn_cvt_pk_fp8_f32(x0, x1, 0, false);
    v = __builtin_amdgcn_cvt_pk_fp8_f32(x2, x3, v, true);
    return (u32)v;
}
__device__ __forceinline__ float dec8(u32 b) {
    f32x2 r = (f32x2)__builtin_amdgcn_cvt_pk_f32_fp8((int)(b & 0xFFu), false);
    return r.x;
}
#else
__device__ __forceinline__ u32 enc1_fp8(float x) {
    if (x >= 448.f) return 0x7Eu;
    if (x < 0.015625f) { int m = (int)(x * 512.f + 0.5f); return (u32)m; }
    u32 u = __float_as_uint(x);
    u += 0x7FFFFu + ((u >> 20) & 1u);
    int e32 = (int)(u >> 23) - 127;
    if (e32 > 8) return 0x7Eu;
    return (u32)(((e32 + 7) << 3) | ((u >> 20) & 7u));
}
__device__ __forceinline__ u32 pack4_fp8(float x0, float x1, float x2, float x3) {
    return enc1_fp8(x0) | (enc1_fp8(x1) << 8) | (enc1_fp8(x2) << 16) | (enc1_fp8(x3) << 24);
}
__device__ __forceinline__ float dec8(u32 b) {
    b &= 0xFFu;
    u32 e = (b >> 3) & 0xFu, m = b & 7u;
    if (e == 0) return (float)m * 0.001953125f;
    return __uint_as_float(((e + 120u) << 23) | (m << 20));
}
#endif

// prep: b==0 clear flags | b in [1,33) emit partials | b==33 trans-sum
__global__ void crf_prep_k(u32* __restrict__ flags,
                           const float* __restrict__ feats, const int* __restrict__ tags,
                           float* __restrict__ part, const float* __restrict__ trans,
                           const int* __restrict__ start_p, float* __restrict__ tsum) {
    __shared__ int tg[2048];
    __shared__ float red[256];
    const int b = blockIdx.x, tid = threadIdx.x;   // 256 threads
    if (b == 0) {
        for (int i = tid; i < NGROUP * 16; i += 256)
            __hip_atomic_store(&flags[i], 0xFFFFu, __ATOMIC_RELAXED, __HIP_MEMORY_SCOPE_AGENT);
    } else if (b < 33) {
        const int bb = b - 1, cch = bb >> 2, jb = bb & 3;
        for (int q = tid; q < 2048; q += 256) tg[q] = tags[cch * 2048 + q];
        __syncthreads();
        const int j = jb * 256 + tid;
        float acc = 0.f;
#pragma unroll 8
        for (int k = 0; k < 2048; ++k) acc += feats[(size_t)tg[k] * NTAGS + j];
        part[cch * NTAGS + j] = acc;
    } else {
        const int start = *start_p;
        float acc = 0.f;
        for (int k = 0; k < 64; ++k) {
            const int t = tid * 64 + k;
            const int prev = (t == 0) ? start : tags[t - 1];
            acc += trans[(size_t)tags[t] * NTAGS + prev];
        }
        red[tid] = acc;
        __syncthreads();
        for (int s = 128; s > 0; s >>= 1) { if (tid < s) red[tid] += red[tid + s]; __syncthreads(); }
        if (tid == 0) *tsum = red[0];
    }
}

__global__ __launch_bounds__(TPB, 1) void crf_scan_k(
    const float* __restrict__ feats, const float* __restrict__ trans,
    u32* __restrict__ wbufs, u32* __restrict__ flags, double* __restrict__ Ssum)
{
    extern __shared__ uint2 wBf[];       // [2][32][128] MFMA B slots (64 KiB dynamic)
    __shared__ u32 cmaxb[2][CPG];
    __shared__ float fbx[8][16][17];     // fallback transpose buffer
    __shared__ int okf, deadf;

    const int tid = threadIdx.x;
    const int l = tid & 63, wv = tid >> 6;
    const int g = blockIdx.x & 31, rank = blockIdx.x >> 5;   // ranks 32 apart -> XCD co-located
    const int bwd = g >> 4, gl = g & 15;
    const int row0 = rank * ROWS;
    const int pc = tid >> 4, pq = tid & 15;    // poller: col 0..31, word-slice 0..15
    const int myc = l & 15, h = l >> 4;
    const int growA = row0 + wv * 16 + myc;
    const int growD = row0 + wv * 16 + h * 4;
    u32* wgrp = wbufs + (size_t)g * (2 * PARW);
    u32* fgrp = flags + g * 16;                // [parity][rank]

    if (tid == 0) { okf = 1; deadf = 0; }
    double Sacc = bwd ? 3.0 : 0.0;             // meaningful for tid < CPG

    // ---- init publish (parity 0), tagless: block's 128 rows x 32 cols ----
    for (int f = tid; f < CPG * 32; f += TPB) {
        const int c = f >> 5, q = f & 31;      // col, word-in-block (4 rows/word)
        u32 pk;
        if (!bwd) pk = 0x38383838u;            // fp8(1.0) x4
        else {
            const int t = (gl * CPG + c) * LSEG + LSEG - 1;
            const int j0 = row0 + 4 * q;
            const float4 fv = *(const float4*)&feats[(size_t)t * NTAGS + j0];
            pk = pack4_fp8(exp2f(fv.x * LOG2E_F - 3.0f), exp2f(fv.y * LOG2E_F - 3.0f),
                           exp2f(fv.z * LOG2E_F - 3.0f), exp2f(fv.w * LOG2E_F - 3.0f));
        }
        __hip_atomic_store(&wgrp[c * 256 + (row0 >> 2) + q], pk,
                           __ATOMIC_RELAXED, __HIP_MEMORY_SCOPE_AGENT);
    }
    asm volatile("s_waitcnt vmcnt(0)" ::: "memory");   // init data acked
    __syncthreads();
    if (tid == 0)
        __hip_atomic_store(&fgrp[0 * 8 + rank], 0u, __ATOMIC_RELAXED, __HIP_MEMORY_SCOPE_AGENT);

    // ---- stage E as persistent A-fragments (fp8, 64 VGPR) — R10-proven ----
    u64 afr[32];
#define STG(KK) { \
        const int kb = (KK) * 32 + h * 8; \
        float x0,x1,x2,x3,x4,x5,x6,x7; \
        if (!bwd) { \
            const float4 t0 = *(const float4*)&trans[(size_t)growA * NTAGS + kb]; \
            const float4 t1 = *(const float4*)&trans[(size_t)growA * NTAGS + kb + 4]; \
            x0=t0.x; x1=t0.y; x2=t0.z; x3=t0.w; x4=t1.x; x5=t1.y; x6=t1.z; x7=t1.w; \
        } else { \
            x0 = trans[(size_t)(kb+0)*NTAGS + growA]; x1 = trans[(size_t)(kb+1)*NTAGS + growA]; \
            x2 = trans[(size_t)(kb+2)*NTAGS + growA]; x3 = trans[(size_t)(kb+3)*NTAGS + growA]; \
            x4 = trans[(size_t)(kb+4)*NTAGS + growA]; x5 = trans[(size_t)(kb+5)*NTAGS + growA]; \
            x6 = trans[(size_t)(kb+6)*NTAGS + growA]; x7 = trans[(size_t)(kb+7)*NTAGS + growA]; \
        } \
        const u32 lo = pack4_fp8(exp2f(x0*LOG2E_F), exp2f(x1*LOG2E_F), exp2f(x2*LOG2E_F), exp2f(x3*LOG2E_F)); \
        const u32 hi = pack4_fp8(exp2f(x4*LOG2E_F), exp2f(x5*LOG2E_F), exp2f(x6*LOG2E_F), exp2f(x7*LOG2E_F)); \
        afr[KK] = (u64)lo | ((u64)hi << 32); }
    REP32(STG, 0)
#undef STG

    // ---- MFMA layout self-check (exact small-int, asymmetric) — R10-proven ----
    {
        float av0,av1,av2,av3,av4,av5,av6,av7, bv0,bv1,bv2,bv3,bv4,bv5,bv6,bv7;
#define TV(I) { const int k = h*8 + (I); \
        const float a_ = (float)((myc + k) & 3); \
        const float b_ = (float)(((k ^ myc) & 3) + 1); \
        if ((I)==0){av0=a_;bv0=b_;} if ((I)==1){av1=a_;bv1=b_;} \
        if ((I)==2){av2=a_;bv2=b_;} if ((I)==3){av3=a_;bv3=b_;} \
        if ((I)==4){av4=a_;bv4=b_;} if ((I)==5){av5=a_;bv5=b_;} \
        if ((I)==6){av6=a_;bv6=b_;} if ((I)==7){av7=a_;bv7=b_;} }
        TV(0) TV(1) TV(2) TV(3) TV(4) TV(5) TV(6) TV(7)
#undef TV
        const u64 at = (u64)pack4_fp8(av0,av1,av2,av3) | ((u64)pack4_fp8(av4,av5,av6,av7) << 32);
        const u64 bt = (u64)pack4_fp8(bv0,bv1,bv2,bv3) | ((u64)pack4_fp8(bv4,bv5,bv6,bv7) << 32);
        f32x4 dz = {0.f, 0.f, 0.f, 0.f};
        dz = __builtin_amdgcn_mfma_f32_16x16x32_fp8_fp8((long)at, (long)bt, dz, 0, 0, 0);
        bool good = true;
#pragma unroll
        for (int v = 0; v < 4; ++v) {
            const int row = h * 4 + v;
            float e = 0.f;
            for (int k = 0; k < 32; ++k)
                e += (float)(((row + k) & 3) * (((k ^ myc) & 3) + 1));
            good = good && (dz[v] == e);
        }
        if (!good) okf = 0;
    }
    __syncthreads();
    const bool fb = (okf == 0);

    for (int tau = 0; tau < LSEG; ++tau) {
        const int p = tau & 1;
        const u32 tag = (u32)tau;

        // feat prefetch (both col-tiles), issued before the flag wait
        float4 ffa = make_float4(0.f,0.f,0.f,0.f), ffb = make_float4(0.f,0.f,0.f,0.f);
        {
            int t = -1;
            if (!bwd) t = tau; else if (tau <= LSEG - 2) t = LSEG - 2 - tau;
            if (t >= 0) {
                const int ca = gl * CPG + myc;
                ffa = *(const float4*)&feats[(size_t)(ca * LSEG + t) * NTAGS + growD];
                ffb = *(const float4*)&feats[(size_t)((ca + 16) * LSEG + t) * NTAGS + growD];
            }
        }

        // ---- 1. flag discovery: wave 0 only ----
        if (wv == 0) {
            int guard = 0;
            u32 fv = tag;
            for (;;) {
                if (l < GPB)
                    fv = __hip_atomic_load(&fgrp[p * 8 + l],
                                           __ATOMIC_RELAXED, __HIP_MEMORY_SCOPE_AGENT);
                if (__all(fv == tag)) break;
                if (++guard > GUARD_MAX) { deadf = 1; break; }
            }
        }
        __syncthreads();               // flags seen; deadf visible
        if (deadf) break;

        // ---- 2. tagless bulk read: 16 words = 64 rows of col pc ----
        u32 w[16];
        {
            const u32* pp = wgrp + p * PARW + pc * 256 + pq * 16;
#pragma unroll
            for (int q = 0; q < 8; ++q) {
                const u64 v = __hip_atomic_load((const u64*)(pp + 2 * q),
                                                __ATOMIC_RELAXED, __HIP_MEMORY_SCOPE_AGENT);
                w[2 * q] = (u32)v; w[2 * q + 1] = (u32)(v >> 32);
            }
        }
        // B-slot writes: kk = 2*pq (+1); slot = (pc>>4)*64 + h2*16 + (pc&15)
        {
            const int sb = (pc >> 4) * 64 + (pc & 15);
#pragma unroll
            for (int h2 = 0; h2 < 4; ++h2) {
                wBf[((size_t)p * 32 + 2 * pq)     * 128 + sb + h2 * 16] = make_uint2(w[2*h2],   w[2*h2+1]);
                wBf[((size_t)p * 32 + 2 * pq + 1) * 128 + sb + h2 * 16] = make_uint2(w[8+2*h2], w[9+2*h2]);
            }
        }
        // col byte-max (fp8 e4m3 positive: integer order = value order)
        {
            u32 bm = 0;
#pragma unroll
            for (int q = 0; q < 16; ++q) {
                bm = max(bm, w[q] & 0xFFu); bm = max(bm, (w[q] >> 8) & 0xFFu);
                bm = max(bm, (w[q] >> 16) & 0xFFu); bm = max(bm, w[q] >> 24);
            }
#pragma unroll
            for (int o = 8; o > 0; o >>= 1) bm = max(bm, (u32)__shfl_xor((int)bm, o));
            if (pq == 0) cmaxb[p][pc] = bm;
        }
        __syncthreads();                 // B1: slots + cmax ready

        const float Cme0 = __log2f(dec8(cmaxb[p][myc])) + COFF;
        const float Cme1 = __log2f(dec8(cmaxb[p][16 + myc])) + COFF;
        if (tid < CPG) Sacc += (double)(__log2f(dec8(cmaxb[p][tid])) + COFF);

        // ---- 3. D = E(128x1024) x w(1024x32): 2 B-tiles, 64 MFMA ----
        f32x4 accA, accB;
        const uint2* wb = &wBf[(size_t)p * 32 * 128];
        if (!fb) {
            f32x4 a0 = {0.f,0.f,0.f,0.f}, a1 = {0.f,0.f,0.f,0.f};
            f32x4 a2 = {0.f,0.f,0.f,0.f}, a3 = {0.f,0.f,0.f,0.f};
#define MF(KK) { const uint2 f0 = wb[(KK)*128 + l]; \
                 const u64 b0 = (u64)f0.x | ((u64)f0.y << 32); \
                 const uint2 f1 = wb[(KK)*128 + 64 + l]; \
                 const u64 b1v = (u64)f1.x | ((u64)f1.y << 32); \
                 if ((KK) & 1) { \
                     a1 = __builtin_amdgcn_mfma_f32_16x16x32_fp8_fp8((long)afr[KK], (long)b0, a1, 0,0,0); \
                     a3 = __builtin_amdgcn_mfma_f32_16x16x32_fp8_fp8((long)afr[KK], (long)b1v, a3, 0,0,0); \
                 } else { \
                     a0 = __builtin_amdgcn_mfma_f32_16x16x32_fp8_fp8((long)afr[KK], (long)b0, a0, 0,0,0); \
                     a2 = __builtin_amdgcn_mfma_f32_16x16x32_fp8_fp8((long)afr[KK], (long)b1v, a2, 0,0,0); \
                 } }
            REP32(MF, 0)
#undef MF
            accA = a0 + a1; accB = a2 + a3;
        } else {
            // layout-assumption-free VALU fallback (slow, correct)
            for (int bt = 0; bt < 2; ++bt) {
                float a16[16];
#pragma unroll
                for (int c = 0; c < 16; ++c) a16[c] = 0.f;
                for (int kk = 0; kk < 32; ++kk) {
                    const u64 av = afr[kk];
                    float ea0 = dec8((u32)av), ea1 = dec8((u32)(av>>8)), ea2 = dec8((u32)(av>>16)), ea3 = dec8((u32)(av>>24));
                    float ea4 = dec8((u32)(av>>32)), ea5 = dec8((u32)(av>>40)), ea6 = dec8((u32)(av>>48)), ea7 = dec8((u32)(av>>56));
#pragma unroll
                    for (int c = 0; c < 16; ++c) {
                        const uint2 bfr = wb[kk * 128 + bt * 64 + h * 16 + c];
                        const u64 bv = (u64)bfr.x | ((u64)bfr.y << 32);
                        float s = fmaf(ea0, dec8((u32)bv), 0.f);
                        s = fmaf(ea1, dec8((u32)(bv>>8)), s);  s = fmaf(ea2, dec8((u32)(bv>>16)), s);
                        s = fmaf(ea3, dec8((u32)(bv>>24)), s); s = fmaf(ea4, dec8((u32)(bv>>32)), s);
                        s = fmaf(ea5, dec8((u32)(bv>>40)), s); s = fmaf(ea6, dec8((u32)(bv>>48)), s);
                        s = fmaf(ea7, dec8((u32)(bv>>56)), s);
                        a16[c] += s;
                    }
                }
#pragma unroll
                for (int c = 0; c < 16; ++c) {
                    float v2 = a16[c];
                    v2 += __shfl_xor(v2, 16); v2 += __shfl_xor(v2, 32);
                    a16[c] = v2;
                }
                if (h == 0) {
#pragma unroll
                    for (int c = 0; c < 16; ++c) fbx[wv][myc][c] = a16[c];
                }
                __syncthreads();
                f32x4 r;
                r.x = fbx[wv][h*4+0][myc]; r.y = fbx[wv][h*4+1][myc];
                r.z = fbx[wv][h*4+2][myc]; r.w = fbx[wv][h*4+3][myc];
                if (bt == 0) accA = r; else accB = r;
                __syncthreads();
            }
        }

        // ---- 4. publish -> parity p^1 (1 word = 4 rows per col-tile); drain; flag ----
        {
            u32* pb = wgrp + (p ^ 1) * PARW;
            const u32 pkA = pack4_fp8(accA.x * exp2f(fmaf(ffa.x, LOG2E_F, -Cme0)),
                                      accA.y * exp2f(fmaf(ffa.y, LOG2E_F, -Cme0)),
                                      accA.z * exp2f(fmaf(ffa.z, LOG2E_F, -Cme0)),
                                      accA.w * exp2f(fmaf(ffa.w, LOG2E_F, -Cme0)));
            const u32 pkB = pack4_fp8(accB.x * exp2f(fmaf(ffb.x, LOG2E_F, -Cme1)),
                                      accB.y * exp2f(fmaf(ffb.y, LOG2E_F, -Cme1)),
                                      accB.z * exp2f(fmaf(ffb.z, LOG2E_F, -Cme1)),
                                      accB.w * exp2f(fmaf(ffb.w, LOG2E_F, -Cme1)));
            __hip_atomic_store(&pb[myc * 256 + (growD >> 2)], pkA,
                               __ATOMIC_RELAXED, __HIP_MEMORY_SCOPE_AGENT);
            __hip_atomic_store(&pb[(16 + myc) * 256 + (growD >> 2)], pkB,
                               __ATOMIC_RELAXED, __HIP_MEMORY_SCOPE_AGENT);
        }
        asm volatile("s_waitcnt vmcnt(0)" ::: "memory");   // this wave's stores acked
        __syncthreads();                                    // all waves acked
        if (tid == 0)
            __hip_atomic_store(&fgrp[(p ^ 1) * 8 + rank], tag + 1u,
                               __ATOMIC_RELAXED, __HIP_MEMORY_SCOPE_AGENT);
    }

    if (rank == 0 && tid < CPG)
        Ssum[bwd * KCH + gl * CPG + tid] = Sacc;
}

// sumy[c]=1'y_c ; dot[c]=z_c.y_{c-1} (c>0), dot[0]=z_0[start]; fin=y_{K-1}.exp(T[stop,:])
__global__ void crf_dots_k(const u32* __restrict__ wbufs, const float* __restrict__ trans,
                           const int* __restrict__ start_p, const int* __restrict__ stop_p,
                           double* __restrict__ dotv, double* __restrict__ sumyv,
                           double* __restrict__ finv)
{
    const int c = blockIdx.x;        // 0..511
    const int tid = threadIdx.x;     // 256 (one word each; 4 rows/word)
    __shared__ double red[256];
    const int GRPW = 2 * PARW;
    const u32* y = wbufs + (size_t)(c >> 5) * GRPW + (c & 31) * 256;
    const u32* z = wbufs + (size_t)(16 + (c >> 5)) * GRPW + (c & 31) * 256;
    const u32* ym1 = (c > 0)
        ? (wbufs + (size_t)((c - 1) >> 5) * GRPW + ((c - 1) & 31) * 256) : nullptr;
    const int stop = *stop_p;

    const u32 wy = y[tid];
    double sy = 0, dt = 0, fn = 0;
#pragma unroll
    for (int b = 0; b < 4; ++b) {
        const double yv = (double)dec8(wy >> (8 * b));
        sy += yv;
        if (c == KCH - 1)
            fn += yv * (double)__expf(trans[(size_t)stop * NTAGS + 4 * tid + b]);
    }
    if (c > 0) {
        const u32 wz = z[tid], wm = ym1[tid];
#pragma unroll
        for (int b = 0; b < 4; ++b)
            dt += (double)dec8(wz >> (8 * b)) * (double)dec8(wm >> (8 * b));
    }
    red[tid] = sy; __syncthreads();
    for (int s = 128; s > 0; s >>= 1) { if (tid < s) red[tid] += red[tid + s]; __syncthreads(); }
    if (tid == 0) sumyv[c] = red[0];
    __syncthreads();
    red[tid] = dt; __syncthreads();
    for (int s = 128; s > 0; s >>= 1) { if (tid < s) red[tid] += red[tid + s]; __syncthreads(); }
    if (tid == 0 && c > 0) dotv[c] = red[0];
    __syncthreads();
    red[tid] = fn; __syncthreads();
    for (int s = 128; s > 0; s >>= 1) { if (tid < s) red[tid] += red[tid + s]; __syncthreads(); }
    if (tid == 0 && c == KCH - 1) finv[0] = red[0];
    if (tid == 0 && c == 0) {
        const int st = *start_p;
        dotv[0] = (double)dec8(z[st >> 2] >> (8 * (st & 3)));
    }
}

// finish: parallel chunk-composition (fs) + output vector
__global__ void crf_finish_k(const double* __restrict__ Ssum, const double* __restrict__ dotv,
                             const double* __restrict__ sumyv, const double* __restrict__ finv,
                             const float* __restrict__ tsum, const float* __restrict__ part,
                             const float* __restrict__ trans, const int* __restrict__ tags,
                             const int* __restrict__ stop_p, float* __restrict__ out)
{
    __shared__ double red[1024];
    __shared__ float fsv;
    const int tid = threadIdx.x;   // 1024
    const double* Ssf = Ssum;
    const double* Ssb = Ssum + KCH;
    double t = 0.0;
    if (tid == 0)
        t = log2(dotv[0]) + Ssb[0] - log2(sumyv[0]) - Ssf[0]
          + log2(finv[0]) + Ssf[KCH - 1];
    else if (tid < KCH)
        t = log2(dotv[tid]) + Ssb[tid] + Ssf[tid - 1] - log2(sumyv[tid]) - Ssf[tid];
    red[tid] = t; __syncthreads();
    for (int s = 512; s > 0; s >>= 1) { if (tid < s) red[tid] += red[tid + s]; __syncthreads(); }
    if (tid == 0) fsv = (float)(LN2_D * red[0]);
    __syncthreads();
    float e = 0.f;
    for (int cc = 0; cc < 8; ++cc) e += part[cc * NTAGS + tid];
    const int stop = *stop_p;
    const int last = tags[SEQLEN - 1];
    out[tid] = fsv - (tsum[0] + e + trans[(size_t)stop * NTAGS + last]);
}

extern "C" void kernel_launch(void* const* d_in, const int* in_sizes, int n_in,
                              void* d_out, int out_size, void* d_ws, size_t ws_size,
                              hipStream_t stream) {
    const float* feats = (const float*)d_in[0];
    const float* trans = (const float*)d_in[1];
    const int* tags    = (const int*)d_in[2];
    const int* start_p = (const int*)d_in[3];
    const int* stop_p  = (const int*)d_in[4];
    float* out = (float*)d_out;

    // ws: wire 2MB | part 32KB | Ssum 8KB | dotv 4KB | sumyv 4KB | finv/tsum | flags 2KB
    char* ws = (char*)d_ws;
    u32* wbufs    = (u32*)(ws + 0);
    float* part   = (float*)(ws + 2097152);
    double* Ssum  = (double*)(ws + 2129920);
    double* dotv  = (double*)(ws + 2138112);
    double* sumyv = (double*)(ws + 2142208);
    double* finv  = (double*)(ws + 2146304);
    float* tsum   = (float*)(ws + 2146312);
    u32* flags    = (u32*)(ws + 2146816);

    (void)hipFuncSetAttribute((const void*)crf_scan_k,
                              hipFuncAttributeMaxDynamicSharedMemorySize, 65536);

    crf_prep_k<<<34, 256, 0, stream>>>(flags, feats, tags, part, trans, start_p, tsum);
    crf_scan_k<<<NGROUP * GPB, TPB, 65536, stream>>>(feats, trans, wbufs, flags, Ssum);
    crf_dots_k<<<KCH, 256, 0, stream>>>(wbufs, trans, start_p, stop_p, dotv, sumyv, finv);
    crf_finish_k<<<1, 1024, 0, stream>>>(Ssum, dotv, sumyv, finv, tsum, part, trans, tags,
                                         stop_p, out);
}